// Round 9
// baseline (50671.063 us; speedup 1.0000x reference)
//
#include <hip/hip_runtime.h>
#include <math.h>

#define VOCAB 20000
#define EDIM  100
#define HDIM  200
#define KTAG  17
#define BATCH 128
#define TLEN  512

// ws layout (float offsets)
static const size_t PROJ_OFF = 0;              // 2 * 20000 * 800 = 32,000,000 floats
static const size_t LSTM_OFF = 32102464;       // 512*128*400 = 26,214,400
static const size_t EM_OFF   = 58316864;       // 512*128*17 = 1,114,112
// W2 (packed Whh, 80,000 float4 = 320,000 floats) overlaps the EM region:
// written by k0, read by k2, dead once k3 overwrites em.
// total = 59,430,976 floats = 237,723,904 bytes

// ---------------- K0: pack Whh — PROVEN L2-friendly layout (R6/R7) ----------------
// W2f4[d][k4][e][g] = Whh_d[row = g*200+e][k = 4*k4 .. 4*k4+3], k4 in [0,50)
// Each k2 lane (e=te) owns its full 64B line (4 gates), read as 4 sectored
// 16B loads -> 99.5% L2 hit (R6/R7 measured). The "fully coalesced" [g][e]
// variant (R8) triggered full-line no-allocate behavior: FETCH 213MB -> 14GB.
__global__ __launch_bounds__(256) void k0_pack(const float* __restrict__ Whh_f,
                                               const float* __restrict__ Whh_b,
                                               float* __restrict__ ws)
{
    int i = blockIdx.x * 256 + threadIdx.x;
    if (i >= 80000) return;
    int d = i / 40000, r = i % 40000;
    int k4 = r / 800, r2 = r % 800;
    int e = r2 >> 2, g = r2 & 3;
    const float* W = d ? Whh_b : Whh_f;
    float4 v = *(const float4*)(W + (size_t)(g * 200 + e) * 200 + 4 * k4);
    ((float4*)(ws + EM_OFF))[i] = v;
}

// ---------------- K1: per-vocab input projections ----------------
__global__ __launch_bounds__(256) void k1_proj(const float* __restrict__ emb,
                                               const float* __restrict__ Wf,
                                               const float* __restrict__ Wb,
                                               float* __restrict__ ws)
{
    int blk = blockIdx.x;
    int d = blk / 313, vt = blk % 313;
    const float* Wih = d ? Wb : Wf;
    float* proj = ws + PROJ_OFF + (size_t)d * VOCAB * 800;
    __shared__ float elds[64][104];
    __shared__ float olds[64][4][26];
    int tid = threadIdx.x;
    for (int idx = tid; idx < 64 * EDIM; idx += 256) {
        int r = idx / EDIM, c = idx % EDIM;
        int v = vt * 64 + r;
        elds[r][c] = (v < VOCAB) ? emb[(size_t)v * EDIM + c] : 0.f;
    }
    __syncthreads();
    int lane = tid & 63, wq = tid >> 6;
    float4 er[25];
#pragma unroll
    for (int i = 0; i < 25; i++) er[i] = *(const float4*)&elds[lane][4 * i];
#pragma unroll 1
    for (int round = 0; round < 8; round++) {
#pragma unroll 1
        for (int m = 0; m < 25; m++) {
            int oj = wq * 200 + round * 25 + m;      // wave-uniform
            int e = oj >> 2, g = oj & 3;
            int row = __builtin_amdgcn_readfirstlane(g * HDIM + e);
            const float* wrow = Wih + (size_t)row * EDIM;
            float acc = 0.f;
#pragma unroll
            for (int i = 0; i < 25; i++) {
                float4 w4 = *(const float4*)&wrow[4 * i];
                acc += w4.x * er[i].x + w4.y * er[i].y + w4.z * er[i].z + w4.w * er[i].w;
            }
            olds[lane][wq][m] = acc;
        }
        __syncthreads();
        for (int idx = tid; idx < 6400; idx += 256) {
            int vloc = idx / 100, rem = idx % 100;
            int q = rem / 25, c = rem % 25;
            int vv = vt * 64 + vloc;
            if (vv < VOCAB) proj[(size_t)vv * 800 + q * 200 + round * 25 + c] = olds[vloc][q][c];
        }
        __syncthreads();
    }
}

// ---------------- K2: bidirectional LSTM, zero cross-wg communication ----------------
// R8 tuning: 32 wgs (2 dirs x 16 tiles of 8 batches). The W-stream cost per
// CU/XCD (TA lookups + L2 delivery) is batch-independent and was the binding
// constraint at 2-4 batches/wg (R6 11.6us/step vs R7 13.3us/step). 8 batches
// amortize it: FMA ~5.3us/step overlaps TA ~5.3us/step on separate pipes.
__global__ __launch_bounds__(512, 2) void k2_lstm(const int* __restrict__ sentence,
                                                  const float* __restrict__ bf,
                                                  const float* __restrict__ bb,
                                                  float* __restrict__ ws)
{
    int w = blockIdx.x;               // 32 = 2 dirs x 16 batch-tiles
    int d = w >> 4, bt = w & 15;
    int B0 = bt * 8;
    const float* bvec = d ? bb : bf;
    const float* proj = ws + PROJ_OFF + (size_t)d * VOCAB * 800;
    const float4* W2 = (const float4*)(ws + EM_OFF) + (size_t)d * 40000;
    float* lstm_out = ws + LSTM_OFF;

    __shared__ float h_lds[2][8][208];   // 13.3 KB
    __shared__ float red[32][204];       // 26.1 KB   kh1 partials [b*4+g][te]
    __shared__ int   tok[8][TLEN];       // 16 KB

    int tid = threadIdx.x;
    int kh = tid >> 8, te = tid & 255;
    bool active = te < 200;

#pragma unroll
    for (int b = 0; b < 8; b++)
        tok[b][tid & 511] = sentence[(size_t)(B0 + b) * TLEN + tid];
    for (int i = tid; i < 8 * 208; i += 512) ((float*)h_lds[0])[i] = 0.f;

    float bias_i = 0.f, bias_f = 0.f, bias_g = 0.f, bias_o = 0.f;
    if (kh == 0 && active) {
        bias_i = bvec[te];
        bias_f = bvec[200 + te];
        bias_g = bvec[400 + te];
        bias_o = bvec[600 + te];
    }
    // per-lane 64B line: entries [e=te][g=0..3] within each k4-block
    const float4* wbase = W2 + (size_t)(kh * 25) * 800 + (active ? te : 0) * 4;
    float c_st[8];
#pragma unroll
    for (int b = 0; b < 8; b++) c_st[b] = 0.f;
    __syncthreads();

#pragma unroll 1
    for (int t = 0; t < TLEN; t++) {
        int t_eff = d ? (TLEN - 1 - t) : t;
        int p = t & 1;

        // xp gathers: issued at step top, consumed after the FMA block (~5us later)
        float4 xp[8];
        if (kh == 0 && active) {
#pragma unroll
            for (int b = 0; b < 8; b++)
                xp[b] = *(const float4*)(proj + (size_t)tok[b][t_eff] * 800 + 4 * te);
        }

        float acc[4][8];
#pragma unroll
        for (int g = 0; g < 4; g++)
#pragma unroll
            for (int b = 0; b < 8; b++) acc[g][b] = 0.f;

        if (active) {
            const float* hpp = &h_lds[p][0][kh * 100];   // batch stride 208 floats
            // W 4-deep, h 2-deep rotating register pipelines over 25 k4-groups
            float4 wv[4][4];
            float4 hv[2][8];
#pragma unroll
            for (int s = 0; s < 4; s++) {
                const float4* wp = wbase + (size_t)s * 800;
                wv[s][0] = wp[0]; wv[s][1] = wp[1]; wv[s][2] = wp[2]; wv[s][3] = wp[3];
            }
#pragma unroll
            for (int hs = 0; hs < 2; hs++)
#pragma unroll
                for (int b = 0; b < 8; b++)
                    hv[hs][b] = *(const float4*)(hpp + b * 208 + 4 * hs);
#pragma unroll
            for (int j = 0; j < 25; j++) {
                const int s = j & 3, hs = j & 1;
#pragma unroll
                for (int b = 0; b < 8; b++) {
                    float4 H = hv[hs][b];
                    acc[0][b] += wv[s][0].x * H.x + wv[s][0].y * H.y + wv[s][0].z * H.z + wv[s][0].w * H.w;
                    acc[1][b] += wv[s][1].x * H.x + wv[s][1].y * H.y + wv[s][1].z * H.z + wv[s][1].w * H.w;
                    acc[2][b] += wv[s][2].x * H.x + wv[s][2].y * H.y + wv[s][2].z * H.z + wv[s][2].w * H.w;
                    acc[3][b] += wv[s][3].x * H.x + wv[s][3].y * H.y + wv[s][3].z * H.z + wv[s][3].w * H.w;
                }
                if (j + 4 < 25) {
                    const float4* wp = wbase + (size_t)(j + 4) * 800;
                    wv[s][0] = wp[0]; wv[s][1] = wp[1]; wv[s][2] = wp[2]; wv[s][3] = wp[3];
                }
                if (j + 2 < 25) {
#pragma unroll
                    for (int b = 0; b < 8; b++)
                        hv[hs][b] = *(const float4*)(hpp + b * 208 + 4 * (j + 2));
                }
            }
        }

        // kh=1 contributes its k-half via LDS
        if (kh == 1 && active) {
#pragma unroll
            for (int b = 0; b < 8; b++) {
                red[b * 4 + 0][te] = acc[0][b];
                red[b * 4 + 1][te] = acc[1][b];
                red[b * 4 + 2][te] = acc[2][b];
                red[b * 4 + 3][te] = acc[3][b];
            }
        }
        __syncthreads();

        if (kh == 0 && active) {
            int pn = p ^ 1;
#pragma unroll
            for (int b = 0; b < 8; b++) {
                float gi = acc[0][b] + red[b * 4 + 0][te] + xp[b].x + bias_i;
                float gf = acc[1][b] + red[b * 4 + 1][te] + xp[b].y + bias_f;
                float gg = acc[2][b] + red[b * 4 + 2][te] + xp[b].z + bias_g;
                float go = acc[3][b] + red[b * 4 + 3][te] + xp[b].w + bias_o;
                float sI = 1.f / (1.f + expf(-gi));
                float sF = 1.f / (1.f + expf(-gf));
                float sO = 1.f / (1.f + expf(-go));
                c_st[b] = sF * c_st[b] + sI * tanhf(gg);
                float hv2 = sO * tanhf(c_st[b]);
                h_lds[pn][b][te] = hv2;
                lstm_out[((size_t)t_eff * BATCH + B0 + b) * 400 + d * 200 + te] = hv2;
            }
        }
        __syncthreads();
    }
}

// ---------------- K3: emissions em = lstm_out @ W_fc^T + b_fc ----------------
__global__ __launch_bounds__(256) void k3_em(const float* __restrict__ Wfc,
                                             const float* __restrict__ bfc,
                                             float* __restrict__ ws)
{
    __shared__ float llds[15][404];
    __shared__ float wlds[17][404];
    const float* lstm = ws + LSTM_OFF;
    float* em = ws + EM_OFF;
    int n0 = blockIdx.x * 15;
    int tid = threadIdx.x;
    for (int idx = tid; idx < 15 * 400; idx += 256) {
        int r = idx / 400, c = idx % 400;
        int n = n0 + r;
        llds[r][c] = (n < BATCH * TLEN) ? lstm[(size_t)n * 400 + c] : 0.f;
    }
    for (int idx = tid; idx < 17 * 400; idx += 256) {
        int r = idx / 400, c = idx % 400;
        wlds[r][c] = Wfc[r * 400 + c];
    }
    __syncthreads();
    if (tid < 255) {
        int tk = tid / 17, k = tid % 17;
        int n = n0 + tk;
        if (n < BATCH * TLEN) {
            float acc = 0.f;
#pragma unroll
            for (int i = 0; i < 100; i++) {
                float4 a  = *(const float4*)&llds[tk][4 * i];
                float4 wv = *(const float4*)&wlds[k][4 * i];
                acc += a.x * wv.x + a.y * wv.y + a.z * wv.z + a.w * wv.w;
            }
            em[(size_t)n * KTAG + k] = acc + bfc[k];
        }
    }
}

// ---------------- K4: bin_scores = mean_t(lstm_out) @ W_bin^T + b_bin ----------------
__global__ __launch_bounds__(256) void k4_bin(const float* __restrict__ Wbin,
                                              const float* __restrict__ bbin,
                                              float* __restrict__ ws,
                                              float* __restrict__ out)
{
    int b = blockIdx.x, tid = threadIdx.x;
    const float* lstm = ws + LSTM_OFF;
    __shared__ float m_lds[400];
    float a0 = 0.f, a1 = 0.f;
#pragma unroll 4
    for (int t = 0; t < TLEN; t++) {
        const float* rowp = lstm + ((size_t)t * BATCH + b) * 400;
        a0 += rowp[tid];
        if (tid < 144) a1 += rowp[256 + tid];
    }
    m_lds[tid] = a0 * (1.f / 512.f);
    if (tid < 144) m_lds[256 + tid] = a1 * (1.f / 512.f);
    __syncthreads();
    int wv = tid >> 6, lane = tid & 63;
    if (wv < 2) {
        float p = 0.f;
        for (int j = lane; j < 400; j += 64) p += m_lds[j] * Wbin[wv * 400 + j];
#pragma unroll
        for (int off = 32; off > 0; off >>= 1) p += __shfl_down(p, off);
        if (lane == 0) out[(size_t)BATCH * TLEN + b * 2 + wv] = p + bbin[wv];
    }
}

// ---------------- K5: masked Viterbi decode + traceback ----------------
__global__ __launch_bounds__(64) void k5_vit(const int* __restrict__ masks,
                                             const float* __restrict__ trans,
                                             const float* __restrict__ startv,
                                             const float* __restrict__ endv,
                                             const float* __restrict__ ws,
                                             float* __restrict__ out)
{
    int b = blockIdx.x, lane = threadIdx.x;
    const float* em = ws + EM_OFF;
    __shared__ float emlds[TLEN * KTAG];
    __shared__ unsigned char bpl[TLEN * KTAG];
    __shared__ int mlds[TLEN];
    __shared__ unsigned char tagl[TLEN];
    __shared__ float slds[KTAG];
    __shared__ float fin[KTAG];

    for (int idx = lane; idx < TLEN * KTAG; idx += 64) {
        int tt = idx / KTAG, j = idx - tt * KTAG;
        emlds[idx] = em[((size_t)tt * BATCH + b) * KTAG + j];
    }
    for (int idx = lane; idx < TLEN; idx += 64) mlds[idx] = masks[(size_t)b * TLEN + idx];
    bool on = lane < KTAG;
    float tr[KTAG];
    if (on) {
#pragma unroll
        for (int i = 0; i < KTAG; i++) tr[i] = trans[i * KTAG + lane];
    }
    __syncthreads();
    float sown = 0.f;
    if (on) { sown = startv[lane] + emlds[lane]; slds[lane] = sown; }
    __syncthreads();
#pragma unroll 1
    for (int t = 1; t < TLEN; t++) {
        int m = mlds[t];
        float ns = sown; int idx = lane;
        if (on) {
            float best = -3.4e38f; int bi = 0;
#pragma unroll
            for (int i = 0; i < KTAG; i++) {
                float vv = slds[i] + tr[i];
                if (vv > best) { best = vv; bi = i; }   // strict > => first max (matches jnp.argmax)
            }
            if (m != 0) { ns = best + emlds[t * KTAG + lane]; idx = bi; }
        }
        __syncthreads();
        if (on) { sown = ns; slds[lane] = ns; bpl[t * KTAG + lane] = (unsigned char)idx; }
        __syncthreads();
    }
    if (on) fin[lane] = sown + endv[lane];
    __syncthreads();
    if (lane == 0) {
        float bb = -3.4e38f; int bi = 0;
#pragma unroll
        for (int i = 0; i < KTAG; i++) if (fin[i] > bb) { bb = fin[i]; bi = i; }
        int cur = bi;
        tagl[TLEN - 1] = (unsigned char)cur;
        for (int t = TLEN - 1; t >= 1; t--) {
            cur = bpl[t * KTAG + cur];
            tagl[t - 1] = (unsigned char)cur;
        }
    }
    __syncthreads();
    for (int s = lane; s < TLEN; s += 64) out[(size_t)b * TLEN + s] = (float)tagl[s];
}

extern "C" void kernel_launch(void* const* d_in, const int* in_sizes, int n_in,
                              void* d_out, int out_size, void* d_ws, size_t ws_size,
                              hipStream_t stream)
{
    (void)in_sizes; (void)n_in; (void)out_size; (void)ws_size;
    const int*   sentence = (const int*)d_in[0];
    const int*   masks    = (const int*)d_in[1];
    const float* emb      = (const float*)d_in[2];
    const float* Wih_f    = (const float*)d_in[3];
    const float* Whh_f    = (const float*)d_in[4];
    const float* b_f      = (const float*)d_in[5];
    const float* Wih_b    = (const float*)d_in[6];
    const float* Whh_b    = (const float*)d_in[7];
    const float* b_b      = (const float*)d_in[8];
    const float* W_fc     = (const float*)d_in[9];
    const float* b_fc     = (const float*)d_in[10];
    const float* W_bin    = (const float*)d_in[11];
    const float* b_bin    = (const float*)d_in[12];
    const float* trans    = (const float*)d_in[13];
    const float* startv   = (const float*)d_in[14];
    const float* endv     = (const float*)d_in[15];
    float* ws  = (float*)d_ws;
    float* out = (float*)d_out;

    k0_pack<<<313, 256, 0, stream>>>(Whh_f, Whh_b, ws);
    k1_proj<<<626, 256, 0, stream>>>(emb, Wih_f, Wih_b, ws);
    k2_lstm<<<32, 512, 0, stream>>>(sentence, b_f, b_b, ws);
    k3_em<<<4370, 256, 0, stream>>>(W_fc, b_fc, ws);
    k4_bin<<<128, 256, 0, stream>>>(W_bin, b_bin, ws, out);
    k5_vit<<<128, 64, 0, stream>>>(masks, trans, startv, endv, ws, out);
}

// Round 10
// 36243.500 us; speedup vs baseline: 1.3981x; 1.3981x over previous
//
#include <hip/hip_runtime.h>
#include <math.h>

#define VOCAB 20000
#define EDIM  100
#define HDIM  200
#define KTAG  17
#define BATCH 128
#define TLEN  512

// ws layout (float offsets)
static const size_t PROJ_OFF = 0;              // 2 * 20000 * 800 = 32,000,000 floats
static const size_t LSTM_OFF = 32102464;       // 512*128*400 = 26,214,400
static const size_t EM_OFF   = 58316864;       // 512*128*17 = 1,114,112
// W2 (packed Whh, 80,000 float4 = 320,000 floats) overlaps the EM region:
// written by k0, read by k2, dead once k3 overwrites em.
// total = 59,430,976 floats = 237,723,904 bytes

// ---------------- K0: pack Whh — PROVEN L2-friendly layout (R6/R7) ----------------
// W2f4[d][k4][e][g] = Whh_d[row = g*200+e][k = 4*k4 .. 4*k4+3], k4 in [0,50)
// Each k2 lane (e=te) owns its full 64B line (4 gates), read as 4 sectored
// 16B loads -> L2-resident (R6/R7 measured 206MB FETCH). The fully-coalesced
// [g][e] variant (R8) caused 14GB HBM refetch. Keep [e][g].
__global__ __launch_bounds__(256) void k0_pack(const float* __restrict__ Whh_f,
                                               const float* __restrict__ Whh_b,
                                               float* __restrict__ ws)
{
    int i = blockIdx.x * 256 + threadIdx.x;
    if (i >= 80000) return;
    int d = i / 40000, r = i % 40000;
    int k4 = r / 800, r2 = r % 800;
    int e = r2 >> 2, g = r2 & 3;
    const float* W = d ? Whh_b : Whh_f;
    float4 v = *(const float4*)(W + (size_t)(g * 200 + e) * 200 + 4 * k4);
    ((float4*)(ws + EM_OFF))[i] = v;
}

// ---------------- K1: per-vocab input projections ----------------
__global__ __launch_bounds__(256) void k1_proj(const float* __restrict__ emb,
                                               const float* __restrict__ Wf,
                                               const float* __restrict__ Wb,
                                               float* __restrict__ ws)
{
    int blk = blockIdx.x;
    int d = blk / 313, vt = blk % 313;
    const float* Wih = d ? Wb : Wf;
    float* proj = ws + PROJ_OFF + (size_t)d * VOCAB * 800;
    __shared__ float elds[64][104];
    __shared__ float olds[64][4][26];
    int tid = threadIdx.x;
    for (int idx = tid; idx < 64 * EDIM; idx += 256) {
        int r = idx / EDIM, c = idx % EDIM;
        int v = vt * 64 + r;
        elds[r][c] = (v < VOCAB) ? emb[(size_t)v * EDIM + c] : 0.f;
    }
    __syncthreads();
    int lane = tid & 63, wq = tid >> 6;
    float4 er[25];
#pragma unroll
    for (int i = 0; i < 25; i++) er[i] = *(const float4*)&elds[lane][4 * i];
#pragma unroll 1
    for (int round = 0; round < 8; round++) {
#pragma unroll 1
        for (int m = 0; m < 25; m++) {
            int oj = wq * 200 + round * 25 + m;      // wave-uniform
            int e = oj >> 2, g = oj & 3;
            int row = __builtin_amdgcn_readfirstlane(g * HDIM + e);
            const float* wrow = Wih + (size_t)row * EDIM;
            float acc = 0.f;
#pragma unroll
            for (int i = 0; i < 25; i++) {
                float4 w4 = *(const float4*)&wrow[4 * i];
                acc += w4.x * er[i].x + w4.y * er[i].y + w4.z * er[i].z + w4.w * er[i].w;
            }
            olds[lane][wq][m] = acc;
        }
        __syncthreads();
        for (int idx = tid; idx < 6400; idx += 256) {
            int vloc = idx / 100, rem = idx % 100;
            int q = rem / 25, c = rem % 25;
            int vv = vt * 64 + vloc;
            if (vv < VOCAB) proj[(size_t)vv * 800 + q * 200 + round * 25 + c] = olds[vloc][q][c];
        }
        __syncthreads();
    }
}

// ---------------- K2: bidirectional LSTM, zero cross-wg communication ----------------
// R9 tuning: SAME per-CU work as R6 (best measured, 11.6us/step) but 1024-thread
// wgs with 4-way k-split -> 16 waves/CU (4/SIMD, vs R6's 2/SIMD). Per-thread
// state halves (wv2+hv2+acc+xp ~115 VGPR, launch_bounds caps 128 -> NO spill,
// R9's 14GB scratch-write failure mode). FMA (2.7us) now hides under the
// W-stream TA path instead of adding to it.
// Thread (kq,te): gates i,f,g,o of h-elem te over k-quarter kq, 4 batches.
__global__ __launch_bounds__(1024, 4) void k2_lstm(const int* __restrict__ sentence,
                                                   const float* __restrict__ bf,
                                                   const float* __restrict__ bb,
                                                   float* __restrict__ ws)
{
    int w = blockIdx.x;               // 64 = 2 dirs x 32 batch-tiles (B=4)
    int d = w >> 5, bt = w & 31;
    int B0 = bt * 4;
    const float* bvec = d ? bb : bf;
    const float* proj = ws + PROJ_OFF + (size_t)d * VOCAB * 800;
    const float4* W2 = (const float4*)(ws + EM_OFF) + (size_t)d * 40000;
    float* lstm_out = ws + LSTM_OFF;

    __shared__ float h_lds[2][4][208];   // 6656 B
    __shared__ float red[3][16][204];    // 39168 B : [kq-1][b*4+g][te]
    __shared__ int   tok[4][TLEN];       // 8192 B   (total 54016 B)

    int tid = threadIdx.x;
    int kq = tid >> 8, te = tid & 255;
    bool active = te < 200;
    int nk4 = (kq < 2) ? 13 : 12;                     // k4-groups this quarter
    int k4s = kq * 12 + (kq < 2 ? kq : 2);            // starts 0,13,26,38

    for (int i = tid; i < 4 * TLEN; i += 1024)
        tok[i >> 9][i & 511] = sentence[(size_t)(B0 + (i >> 9)) * TLEN + (i & 511)];
    for (int i = tid; i < 4 * 208; i += 1024) ((float*)h_lds[0])[i] = 0.f;

    float bias_i = 0.f, bias_f = 0.f, bias_g = 0.f, bias_o = 0.f;
    if (kq == 0 && active) {
        bias_i = bvec[te];
        bias_f = bvec[200 + te];
        bias_g = bvec[400 + te];
        bias_o = bvec[600 + te];
    }
    // W2 float4 index: (k4*200 + e)*4 + g ; lane te owns its 64B line per k4
    const float4* wbase = W2 + ((size_t)k4s * 200 + (active ? te : 0)) * 4;
    float c_st[4];
#pragma unroll
    for (int b = 0; b < 4; b++) c_st[b] = 0.f;
    __syncthreads();

#pragma unroll 1
    for (int t = 0; t < TLEN; t++) {
        int t_eff = d ? (TLEN - 1 - t) : t;
        int p = t & 1;

        float4 xp[4];
        if (kq == 0 && active) {
#pragma unroll
            for (int b = 0; b < 4; b++)
                xp[b] = *(const float4*)(proj + (size_t)tok[b][t_eff] * 800 + 4 * te);
        }

        float acc[4][4];                 // [gate][batch]
#pragma unroll
        for (int g = 0; g < 4; g++)
#pragma unroll
            for (int b = 0; b < 4; b++) acc[g][b] = 0.f;

        if (active) {
            float4 wv0[4], wv1[4], hv0[4], hv1[4];
            const float4* wpA = wbase;               // group k4s+0
            const float4* wpB = wbase + 800;         // group k4s+1
            wv0[0] = wpA[0]; wv0[1] = wpA[1]; wv0[2] = wpA[2]; wv0[3] = wpA[3];
            wv1[0] = wpB[0]; wv1[1] = wpB[1]; wv1[2] = wpB[2]; wv1[3] = wpB[3];
#pragma unroll
            for (int b = 0; b < 4; b++) {
                hv0[b] = *(const float4*)&h_lds[p][b][4 * k4s];
                hv1[b] = *(const float4*)&h_lds[p][b][4 * (k4s + 1)];
            }
#define K2_STEP(WV, HV)                                                          \
            {                                                                     \
                _Pragma("unroll")                                                 \
                for (int b = 0; b < 4; b++) {                                     \
                    float4 H = HV[b];                                             \
                    acc[0][b] += WV[0].x*H.x + WV[0].y*H.y + WV[0].z*H.z + WV[0].w*H.w; \
                    acc[1][b] += WV[1].x*H.x + WV[1].y*H.y + WV[1].z*H.z + WV[1].w*H.w; \
                    acc[2][b] += WV[2].x*H.x + WV[2].y*H.y + WV[2].z*H.z + WV[2].w*H.w; \
                    acc[3][b] += WV[3].x*H.x + WV[3].y*H.y + WV[3].z*H.z + WV[3].w*H.w; \
                }                                                                 \
            }
#define K2_PREF(WV, HV, WP, J)                                                    \
            if ((J) < nk4) {                                                      \
                WP += 1600;                                                       \
                WV[0] = WP[0]; WV[1] = WP[1]; WV[2] = WP[2]; WV[3] = WP[3];       \
                _Pragma("unroll")                                                 \
                for (int b = 0; b < 4; b++)                                       \
                    HV[b] = *(const float4*)&h_lds[p][b][4 * (k4s + (J))];        \
            }
#pragma unroll 1
            for (int jp = 0; jp < 6; jp++) {
                int j0 = 2 * jp;
                K2_STEP(wv0, hv0)
                K2_PREF(wv0, hv0, wpA, j0 + 2)
                K2_STEP(wv1, hv1)
                K2_PREF(wv1, hv1, wpB, j0 + 3)
            }
            if (nk4 == 13) { K2_STEP(wv0, hv0) }     // group 12 sits in slot 0
#undef K2_STEP
#undef K2_PREF
        }

        if (kq != 0 && active) {
#pragma unroll
            for (int b = 0; b < 4; b++) {
                red[kq - 1][b * 4 + 0][te] = acc[0][b];
                red[kq - 1][b * 4 + 1][te] = acc[1][b];
                red[kq - 1][b * 4 + 2][te] = acc[2][b];
                red[kq - 1][b * 4 + 3][te] = acc[3][b];
            }
        }
        __syncthreads();

        if (kq == 0 && active) {
            int pn = p ^ 1;
#pragma unroll
            for (int b = 0; b < 4; b++) {
                float gi = acc[0][b] + red[0][b*4+0][te] + red[1][b*4+0][te] + red[2][b*4+0][te] + xp[b].x + bias_i;
                float gf = acc[1][b] + red[0][b*4+1][te] + red[1][b*4+1][te] + red[2][b*4+1][te] + xp[b].y + bias_f;
                float gg = acc[2][b] + red[0][b*4+2][te] + red[1][b*4+2][te] + red[2][b*4+2][te] + xp[b].z + bias_g;
                float go = acc[3][b] + red[0][b*4+3][te] + red[1][b*4+3][te] + red[2][b*4+3][te] + xp[b].w + bias_o;
                float sI = 1.f / (1.f + expf(-gi));
                float sF = 1.f / (1.f + expf(-gf));
                float sO = 1.f / (1.f + expf(-go));
                c_st[b] = sF * c_st[b] + sI * tanhf(gg);
                float hv = sO * tanhf(c_st[b]);
                h_lds[pn][b][te] = hv;
                lstm_out[((size_t)t_eff * BATCH + B0 + b) * 400 + d * 200 + te] = hv;
            }
        }
        __syncthreads();
    }
}

// ---------------- K3: emissions em = lstm_out @ W_fc^T + b_fc ----------------
__global__ __launch_bounds__(256) void k3_em(const float* __restrict__ Wfc,
                                             const float* __restrict__ bfc,
                                             float* __restrict__ ws)
{
    __shared__ float llds[15][404];
    __shared__ float wlds[17][404];
    const float* lstm = ws + LSTM_OFF;
    float* em = ws + EM_OFF;
    int n0 = blockIdx.x * 15;
    int tid = threadIdx.x;
    for (int idx = tid; idx < 15 * 400; idx += 256) {
        int r = idx / 400, c = idx % 400;
        int n = n0 + r;
        llds[r][c] = (n < BATCH * TLEN) ? lstm[(size_t)n * 400 + c] : 0.f;
    }
    for (int idx = tid; idx < 17 * 400; idx += 256) {
        int r = idx / 400, c = idx % 400;
        wlds[r][c] = Wfc[r * 400 + c];
    }
    __syncthreads();
    if (tid < 255) {
        int tk = tid / 17, k = tid % 17;
        int n = n0 + tk;
        if (n < BATCH * TLEN) {
            float acc = 0.f;
#pragma unroll
            for (int i = 0; i < 100; i++) {
                float4 a  = *(const float4*)&llds[tk][4 * i];
                float4 wv = *(const float4*)&wlds[k][4 * i];
                acc += a.x * wv.x + a.y * wv.y + a.z * wv.z + a.w * wv.w;
            }
            em[(size_t)n * KTAG + k] = acc + bfc[k];
        }
    }
}

// ---------------- K4: bin_scores = mean_t(lstm_out) @ W_bin^T + b_bin ----------------
__global__ __launch_bounds__(256) void k4_bin(const float* __restrict__ Wbin,
                                              const float* __restrict__ bbin,
                                              float* __restrict__ ws,
                                              float* __restrict__ out)
{
    int b = blockIdx.x, tid = threadIdx.x;
    const float* lstm = ws + LSTM_OFF;
    __shared__ float m_lds[400];
    float a0 = 0.f, a1 = 0.f;
#pragma unroll 4
    for (int t = 0; t < TLEN; t++) {
        const float* rowp = lstm + ((size_t)t * BATCH + b) * 400;
        a0 += rowp[tid];
        if (tid < 144) a1 += rowp[256 + tid];
    }
    m_lds[tid] = a0 * (1.f / 512.f);
    if (tid < 144) m_lds[256 + tid] = a1 * (1.f / 512.f);
    __syncthreads();
    int wv = tid >> 6, lane = tid & 63;
    if (wv < 2) {
        float p = 0.f;
        for (int j = lane; j < 400; j += 64) p += m_lds[j] * Wbin[wv * 400 + j];
#pragma unroll
        for (int off = 32; off > 0; off >>= 1) p += __shfl_down(p, off);
        if (lane == 0) out[(size_t)BATCH * TLEN + b * 2 + wv] = p + bbin[wv];
    }
}

// ---------------- K5: masked Viterbi decode + traceback ----------------
__global__ __launch_bounds__(64) void k5_vit(const int* __restrict__ masks,
                                             const float* __restrict__ trans,
                                             const float* __restrict__ startv,
                                             const float* __restrict__ endv,
                                             const float* __restrict__ ws,
                                             float* __restrict__ out)
{
    int b = blockIdx.x, lane = threadIdx.x;
    const float* em = ws + EM_OFF;
    __shared__ float emlds[TLEN * KTAG];
    __shared__ unsigned char bpl[TLEN * KTAG];
    __shared__ int mlds[TLEN];
    __shared__ unsigned char tagl[TLEN];
    __shared__ float slds[KTAG];
    __shared__ float fin[KTAG];

    for (int idx = lane; idx < TLEN * KTAG; idx += 64) {
        int tt = idx / KTAG, j = idx - tt * KTAG;
        emlds[idx] = em[((size_t)tt * BATCH + b) * KTAG + j];
    }
    for (int idx = lane; idx < TLEN; idx += 64) mlds[idx] = masks[(size_t)b * TLEN + idx];
    bool on = lane < KTAG;
    float tr[KTAG];
    if (on) {
#pragma unroll
        for (int i = 0; i < KTAG; i++) tr[i] = trans[i * KTAG + lane];
    }
    __syncthreads();
    float sown = 0.f;
    if (on) { sown = startv[lane] + emlds[lane]; slds[lane] = sown; }
    __syncthreads();
#pragma unroll 1
    for (int t = 1; t < TLEN; t++) {
        int m = mlds[t];
        float ns = sown; int idx = lane;
        if (on) {
            float best = -3.4e38f; int bi = 0;
#pragma unroll
            for (int i = 0; i < KTAG; i++) {
                float vv = slds[i] + tr[i];
                if (vv > best) { best = vv; bi = i; }   // strict > => first max (matches jnp.argmax)
            }
            if (m != 0) { ns = best + emlds[t * KTAG + lane]; idx = bi; }
        }
        __syncthreads();
        if (on) { sown = ns; slds[lane] = ns; bpl[t * KTAG + lane] = (unsigned char)idx; }
        __syncthreads();
    }
    if (on) fin[lane] = sown + endv[lane];
    __syncthreads();
    if (lane == 0) {
        float bb = -3.4e38f; int bi = 0;
#pragma unroll
        for (int i = 0; i < KTAG; i++) if (fin[i] > bb) { bb = fin[i]; bi = i; }
        int cur = bi;
        tagl[TLEN - 1] = (unsigned char)cur;
        for (int t = TLEN - 1; t >= 1; t--) {
            cur = bpl[t * KTAG + cur];
            tagl[t - 1] = (unsigned char)cur;
        }
    }
    __syncthreads();
    for (int s = lane; s < TLEN; s += 64) out[(size_t)b * TLEN + s] = (float)tagl[s];
}

extern "C" void kernel_launch(void* const* d_in, const int* in_sizes, int n_in,
                              void* d_out, int out_size, void* d_ws, size_t ws_size,
                              hipStream_t stream)
{
    (void)in_sizes; (void)n_in; (void)out_size; (void)ws_size;
    const int*   sentence = (const int*)d_in[0];
    const int*   masks    = (const int*)d_in[1];
    const float* emb      = (const float*)d_in[2];
    const float* Wih_f    = (const float*)d_in[3];
    const float* Whh_f    = (const float*)d_in[4];
    const float* b_f      = (const float*)d_in[5];
    const float* Wih_b    = (const float*)d_in[6];
    const float* Whh_b    = (const float*)d_in[7];
    const float* b_b      = (const float*)d_in[8];
    const float* W_fc     = (const float*)d_in[9];
    const float* b_fc     = (const float*)d_in[10];
    const float* W_bin    = (const float*)d_in[11];
    const float* b_bin    = (const float*)d_in[12];
    const float* trans    = (const float*)d_in[13];
    const float* startv   = (const float*)d_in[14];
    const float* endv     = (const float*)d_in[15];
    float* ws  = (float*)d_ws;
    float* out = (float*)d_out;

    k0_pack<<<313, 256, 0, stream>>>(Whh_f, Whh_b, ws);
    k1_proj<<<626, 256, 0, stream>>>(emb, Wih_f, Wih_b, ws);
    k2_lstm<<<64, 1024, 0, stream>>>(sentence, b_f, b_b, ws);
    k3_em<<<4370, 256, 0, stream>>>(W_fc, b_fc, ws);
    k4_bin<<<128, 256, 0, stream>>>(W_bin, b_bin, ws, out);
    k5_vit<<<128, 64, 0, stream>>>(masks, trans, startv, endv, ws, out);
}

// Round 11
// 9543.507 us; speedup vs baseline: 5.3095x; 3.7977x over previous
//
#include <hip/hip_runtime.h>
#include <math.h>

#define VOCAB 20000
#define EDIM  100
#define HDIM  200
#define KTAG  17
#define BATCH 128
#define TLEN  512

// ws layout (float offsets)
static const size_t PROJ_OFF = 0;              // 2 * 20000 * 800 = 32,000,000 floats
static const size_t LSTM_OFF = 32102464;       // 512*128*400 = 26,214,400
static const size_t EM_OFF   = 58316864;       // 512*128*17 = 1,114,112
// W2 (packed Whh, 80,000 float4 = 320,000 floats) overlaps the EM region:
// written by k0, read by k2, dead once k3 overwrites em.
// total = 59,430,976 floats = 237,723,904 bytes

// ---------------- K0: pack Whh — PROVEN L2-friendly layout (R6/R7) ----------------
// W2f4[d][k4][e][g] = Whh_d[row = g*200+e][k = 4*k4 .. 4*k4+3], k4 in [0,50)
// Each k2 lane (e=te) owns its full 64B line (4 gates), read as 4 sectored
// 16B loads -> L2-resident (R6/R7: 206MB FETCH). Fully-coalesced [g][e] (R8)
// caused 14GB HBM refetch. Keep [e][g].
__global__ __launch_bounds__(256) void k0_pack(const float* __restrict__ Whh_f,
                                               const float* __restrict__ Whh_b,
                                               float* __restrict__ ws)
{
    int i = blockIdx.x * 256 + threadIdx.x;
    if (i >= 80000) return;
    int d = i / 40000, r = i % 40000;
    int k4 = r / 800, r2 = r % 800;
    int e = r2 >> 2, g = r2 & 3;
    const float* W = d ? Whh_b : Whh_f;
    float4 v = *(const float4*)(W + (size_t)(g * 200 + e) * 200 + 4 * k4);
    ((float4*)(ws + EM_OFF))[i] = v;
}

// ---------------- K1: per-vocab input projections ----------------
__global__ __launch_bounds__(256) void k1_proj(const float* __restrict__ emb,
                                               const float* __restrict__ Wf,
                                               const float* __restrict__ Wb,
                                               float* __restrict__ ws)
{
    int blk = blockIdx.x;
    int d = blk / 313, vt = blk % 313;
    const float* Wih = d ? Wb : Wf;
    float* proj = ws + PROJ_OFF + (size_t)d * VOCAB * 800;
    __shared__ float elds[64][104];
    __shared__ float olds[64][4][26];
    int tid = threadIdx.x;
    for (int idx = tid; idx < 64 * EDIM; idx += 256) {
        int r = idx / EDIM, c = idx % EDIM;
        int v = vt * 64 + r;
        elds[r][c] = (v < VOCAB) ? emb[(size_t)v * EDIM + c] : 0.f;
    }
    __syncthreads();
    int lane = tid & 63, wq = tid >> 6;
    float4 er[25];
#pragma unroll
    for (int i = 0; i < 25; i++) er[i] = *(const float4*)&elds[lane][4 * i];
#pragma unroll 1
    for (int round = 0; round < 8; round++) {
#pragma unroll 1
        for (int m = 0; m < 25; m++) {
            int oj = wq * 200 + round * 25 + m;      // wave-uniform
            int e = oj >> 2, g = oj & 3;
            int row = __builtin_amdgcn_readfirstlane(g * HDIM + e);
            const float* wrow = Wih + (size_t)row * EDIM;
            float acc = 0.f;
#pragma unroll
            for (int i = 0; i < 25; i++) {
                float4 w4 = *(const float4*)&wrow[4 * i];
                acc += w4.x * er[i].x + w4.y * er[i].y + w4.z * er[i].z + w4.w * er[i].w;
            }
            olds[lane][wq][m] = acc;
        }
        __syncthreads();
        for (int idx = tid; idx < 6400; idx += 256) {
            int vloc = idx / 100, rem = idx % 100;
            int q = rem / 25, c = rem % 25;
            int vv = vt * 64 + vloc;
            if (vv < VOCAB) proj[(size_t)vv * 800 + q * 200 + round * 25 + c] = olds[vloc][q][c];
        }
        __syncthreads();
    }
}

// ---------------- K2: bidirectional LSTM, zero cross-wg communication ----------------
// R10 retry with correct register budget: 64 wgs x 1024 threads (16 waves/CU =
// 4/SIMD for TLP), 4-way k-split, B=4. Single-arg __launch_bounds__(1024) ->
// compiler MUST fit 16 waves -> 128 VGPR cap (R10's (1024,4) resolved to 64
// VGPR -> 7.2GB spill). Per-thread state trimmed to ~105 VGPR: W 2-ptr x 2-deep
// register pipeline (global, needs latency cover), h single-buffered from LDS.
__global__ __launch_bounds__(1024) void k2_lstm(const int* __restrict__ sentence,
                                                const float* __restrict__ bf,
                                                const float* __restrict__ bb,
                                                float* __restrict__ ws)
{
    int w = blockIdx.x;               // 64 = 2 dirs x 16 batch-tiles (B=4)... (2x32)
    int d = w >> 5, bt = w & 31;
    int B0 = bt * 4;
    const float* bvec = d ? bb : bf;
    const float* proj = ws + PROJ_OFF + (size_t)d * VOCAB * 800;
    const float4* W2 = (const float4*)(ws + EM_OFF) + (size_t)d * 40000;
    float* lstm_out = ws + LSTM_OFF;

    __shared__ float h_lds[2][4][208];   // 6656 B
    __shared__ float red[3][16][204];    // 39168 B : [kq-1][b*4+g][te]
    __shared__ int   tok[4][TLEN];       // 8192 B   (total ~54 KB)

    int tid = threadIdx.x;
    int kq = tid >> 8, te = tid & 255;
    bool active = te < 200;
    int nk4 = (kq < 2) ? 13 : 12;                     // k4-groups this quarter
    int k4s = kq * 12 + (kq < 2 ? kq : 2);            // starts 0,13,26,38

    for (int i = tid; i < 4 * TLEN; i += 1024)
        tok[i >> 9][i & 511] = sentence[(size_t)(B0 + (i >> 9)) * TLEN + (i & 511)];
    for (int i = tid; i < 4 * 208; i += 1024) ((float*)h_lds[0])[i] = 0.f;

    float bias_i = 0.f, bias_f = 0.f, bias_g = 0.f, bias_o = 0.f;
    if (kq == 0 && active) {
        bias_i = bvec[te];
        bias_f = bvec[200 + te];
        bias_g = bvec[400 + te];
        bias_o = bvec[600 + te];
    }
    // W2 float4 index: (k4*200 + e)*4 + g ; lane te owns its 64B line per k4
    const float4* wbase = W2 + ((size_t)k4s * 200 + (active ? te : 0)) * 4;
    float c_st[4];
#pragma unroll
    for (int b = 0; b < 4; b++) c_st[b] = 0.f;
    __syncthreads();

#pragma unroll 1
    for (int t = 0; t < TLEN; t++) {
        int t_eff = d ? (TLEN - 1 - t) : t;
        int p = t & 1;

        float4 xp[4];
        if (kq == 0 && active) {
#pragma unroll
            for (int b = 0; b < 4; b++)
                xp[b] = *(const float4*)(proj + (size_t)tok[b][t_eff] * 800 + 4 * te);
        }

        float acc[4][4];                 // [gate][batch]
#pragma unroll
        for (int g = 0; g < 4; g++)
#pragma unroll
            for (int b = 0; b < 4; b++) acc[g][b] = 0.f;

        if (active) {
            float4 wv0[4], wv1[4], hv[4];
            const float4* wpA = wbase;               // even groups: k4s+0,2,4,...
            const float4* wpB = wbase + 800;         // odd groups:  k4s+1,3,5,...
            wv0[0] = wpA[0]; wv0[1] = wpA[1]; wv0[2] = wpA[2]; wv0[3] = wpA[3];
            wv1[0] = wpB[0]; wv1[1] = wpB[1]; wv1[2] = wpB[2]; wv1[3] = wpB[3];
#define K2_STEP(WV, J)                                                            \
            {                                                                     \
                _Pragma("unroll")                                                 \
                for (int b = 0; b < 4; b++)                                       \
                    hv[b] = *(const float4*)&h_lds[p][b][4 * (k4s + (J))];        \
                _Pragma("unroll")                                                 \
                for (int b = 0; b < 4; b++) {                                     \
                    float4 H = hv[b];                                             \
                    acc[0][b] += WV[0].x*H.x + WV[0].y*H.y + WV[0].z*H.z + WV[0].w*H.w; \
                    acc[1][b] += WV[1].x*H.x + WV[1].y*H.y + WV[1].z*H.z + WV[1].w*H.w; \
                    acc[2][b] += WV[2].x*H.x + WV[2].y*H.y + WV[2].z*H.z + WV[2].w*H.w; \
                    acc[3][b] += WV[3].x*H.x + WV[3].y*H.y + WV[3].z*H.z + WV[3].w*H.w; \
                }                                                                 \
            }
#define K2_PREF(WV, WP, J)                                                        \
            if ((J) < nk4) {                                                      \
                WP += 1600;                                                       \
                WV[0] = WP[0]; WV[1] = WP[1]; WV[2] = WP[2]; WV[3] = WP[3];       \
            }
#pragma unroll 1
            for (int jp = 0; jp < 6; jp++) {
                int j0 = 2 * jp;
                K2_STEP(wv0, j0)
                K2_PREF(wv0, wpA, j0 + 2)
                K2_STEP(wv1, j0 + 1)
                K2_PREF(wv1, wpB, j0 + 3)
            }
            if (nk4 == 13) { K2_STEP(wv0, 12) }      // group 12 sits in stream A
#undef K2_STEP
#undef K2_PREF
        }

        if (kq != 0 && active) {
#pragma unroll
            for (int b = 0; b < 4; b++) {
                red[kq - 1][b * 4 + 0][te] = acc[0][b];
                red[kq - 1][b * 4 + 1][te] = acc[1][b];
                red[kq - 1][b * 4 + 2][te] = acc[2][b];
                red[kq - 1][b * 4 + 3][te] = acc[3][b];
            }
        }
        __syncthreads();

        if (kq == 0 && active) {
            int pn = p ^ 1;
#pragma unroll
            for (int b = 0; b < 4; b++) {
                float gi = acc[0][b] + red[0][b*4+0][te] + red[1][b*4+0][te] + red[2][b*4+0][te] + xp[b].x + bias_i;
                float gf = acc[1][b] + red[0][b*4+1][te] + red[1][b*4+1][te] + red[2][b*4+1][te] + xp[b].y + bias_f;
                float gg = acc[2][b] + red[0][b*4+2][te] + red[1][b*4+2][te] + red[2][b*4+2][te] + xp[b].z + bias_g;
                float go = acc[3][b] + red[0][b*4+3][te] + red[1][b*4+3][te] + red[2][b*4+3][te] + xp[b].w + bias_o;
                float sI = 1.f / (1.f + expf(-gi));
                float sF = 1.f / (1.f + expf(-gf));
                float sO = 1.f / (1.f + expf(-go));
                c_st[b] = sF * c_st[b] + sI * tanhf(gg);
                float hv2 = sO * tanhf(c_st[b]);
                h_lds[pn][b][te] = hv2;
                lstm_out[((size_t)t_eff * BATCH + B0 + b) * 400 + d * 200 + te] = hv2;
            }
        }
        __syncthreads();
    }
}

// ---------------- K3: emissions em = lstm_out @ W_fc^T + b_fc ----------------
__global__ __launch_bounds__(256) void k3_em(const float* __restrict__ Wfc,
                                             const float* __restrict__ bfc,
                                             float* __restrict__ ws)
{
    __shared__ float llds[15][404];
    __shared__ float wlds[17][404];
    const float* lstm = ws + LSTM_OFF;
    float* em = ws + EM_OFF;
    int n0 = blockIdx.x * 15;
    int tid = threadIdx.x;
    for (int idx = tid; idx < 15 * 400; idx += 256) {
        int r = idx / 400, c = idx % 400;
        int n = n0 + r;
        llds[r][c] = (n < BATCH * TLEN) ? lstm[(size_t)n * 400 + c] : 0.f;
    }
    for (int idx = tid; idx < 17 * 400; idx += 256) {
        int r = idx / 400, c = idx % 400;
        wlds[r][c] = Wfc[r * 400 + c];
    }
    __syncthreads();
    if (tid < 255) {
        int tk = tid / 17, k = tid % 17;
        int n = n0 + tk;
        if (n < BATCH * TLEN) {
            float acc = 0.f;
#pragma unroll
            for (int i = 0; i < 100; i++) {
                float4 a  = *(const float4*)&llds[tk][4 * i];
                float4 wv = *(const float4*)&wlds[k][4 * i];
                acc += a.x * wv.x + a.y * wv.y + a.z * wv.z + a.w * wv.w;
            }
            em[(size_t)n * KTAG + k] = acc + bfc[k];
        }
    }
}

// ---------------- K4: bin_scores = mean_t(lstm_out) @ W_bin^T + b_bin ----------------
__global__ __launch_bounds__(256) void k4_bin(const float* __restrict__ Wbin,
                                              const float* __restrict__ bbin,
                                              float* __restrict__ ws,
                                              float* __restrict__ out)
{
    int b = blockIdx.x, tid = threadIdx.x;
    const float* lstm = ws + LSTM_OFF;
    __shared__ float m_lds[400];
    float a0 = 0.f, a1 = 0.f;
#pragma unroll 4
    for (int t = 0; t < TLEN; t++) {
        const float* rowp = lstm + ((size_t)t * BATCH + b) * 400;
        a0 += rowp[tid];
        if (tid < 144) a1 += rowp[256 + tid];
    }
    m_lds[tid] = a0 * (1.f / 512.f);
    if (tid < 144) m_lds[256 + tid] = a1 * (1.f / 512.f);
    __syncthreads();
    int wv = tid >> 6, lane = tid & 63;
    if (wv < 2) {
        float p = 0.f;
        for (int j = lane; j < 400; j += 64) p += m_lds[j] * Wbin[wv * 400 + j];
#pragma unroll
        for (int off = 32; off > 0; off >>= 1) p += __shfl_down(p, off);
        if (lane == 0) out[(size_t)BATCH * TLEN + b * 2 + wv] = p + bbin[wv];
    }
}

// ---------------- K5: masked Viterbi decode + traceback ----------------
__global__ __launch_bounds__(64) void k5_vit(const int* __restrict__ masks,
                                             const float* __restrict__ trans,
                                             const float* __restrict__ startv,
                                             const float* __restrict__ endv,
                                             const float* __restrict__ ws,
                                             float* __restrict__ out)
{
    int b = blockIdx.x, lane = threadIdx.x;
    const float* em = ws + EM_OFF;
    __shared__ float emlds[TLEN * KTAG];
    __shared__ unsigned char bpl[TLEN * KTAG];
    __shared__ int mlds[TLEN];
    __shared__ unsigned char tagl[TLEN];
    __shared__ float slds[KTAG];
    __shared__ float fin[KTAG];

    for (int idx = lane; idx < TLEN * KTAG; idx += 64) {
        int tt = idx / KTAG, j = idx - tt * KTAG;
        emlds[idx] = em[((size_t)tt * BATCH + b) * KTAG + j];
    }
    for (int idx = lane; idx < TLEN; idx += 64) mlds[idx] = masks[(size_t)b * TLEN + idx];
    bool on = lane < KTAG;
    float tr[KTAG];
    if (on) {
#pragma unroll
        for (int i = 0; i < KTAG; i++) tr[i] = trans[i * KTAG + lane];
    }
    __syncthreads();
    float sown = 0.f;
    if (on) { sown = startv[lane] + emlds[lane]; slds[lane] = sown; }
    __syncthreads();
#pragma unroll 1
    for (int t = 1; t < TLEN; t++) {
        int m = mlds[t];
        float ns = sown; int idx = lane;
        if (on) {
            float best = -3.4e38f; int bi = 0;
#pragma unroll
            for (int i = 0; i < KTAG; i++) {
                float vv = slds[i] + tr[i];
                if (vv > best) { best = vv; bi = i; }   // strict > => first max (matches jnp.argmax)
            }
            if (m != 0) { ns = best + emlds[t * KTAG + lane]; idx = bi; }
        }
        __syncthreads();
        if (on) { sown = ns; slds[lane] = ns; bpl[t * KTAG + lane] = (unsigned char)idx; }
        __syncthreads();
    }
    if (on) fin[lane] = sown + endv[lane];
    __syncthreads();
    if (lane == 0) {
        float bb = -3.4e38f; int bi = 0;
#pragma unroll
        for (int i = 0; i < KTAG; i++) if (fin[i] > bb) { bb = fin[i]; bi = i; }
        int cur = bi;
        tagl[TLEN - 1] = (unsigned char)cur;
        for (int t = TLEN - 1; t >= 1; t--) {
            cur = bpl[t * KTAG + cur];
            tagl[t - 1] = (unsigned char)cur;
        }
    }
    __syncthreads();
    for (int s = lane; s < TLEN; s += 64) out[(size_t)b * TLEN + s] = (float)tagl[s];
}

extern "C" void kernel_launch(void* const* d_in, const int* in_sizes, int n_in,
                              void* d_out, int out_size, void* d_ws, size_t ws_size,
                              hipStream_t stream)
{
    (void)in_sizes; (void)n_in; (void)out_size; (void)ws_size;
    const int*   sentence = (const int*)d_in[0];
    const int*   masks    = (const int*)d_in[1];
    const float* emb      = (const float*)d_in[2];
    const float* Wih_f    = (const float*)d_in[3];
    const float* Whh_f    = (const float*)d_in[4];
    const float* b_f      = (const float*)d_in[5];
    const float* Wih_b    = (const float*)d_in[6];
    const float* Whh_b    = (const float*)d_in[7];
    const float* b_b      = (const float*)d_in[8];
    const float* W_fc     = (const float*)d_in[9];
    const float* b_fc     = (const float*)d_in[10];
    const float* W_bin    = (const float*)d_in[11];
    const float* b_bin    = (const float*)d_in[12];
    const float* trans    = (const float*)d_in[13];
    const float* startv   = (const float*)d_in[14];
    const float* endv     = (const float*)d_in[15];
    float* ws  = (float*)d_ws;
    float* out = (float*)d_out;

    k0_pack<<<313, 256, 0, stream>>>(Whh_f, Whh_b, ws);
    k1_proj<<<626, 256, 0, stream>>>(emb, Wih_f, Wih_b, ws);
    k2_lstm<<<64, 1024, 0, stream>>>(sentence, b_f, b_b, ws);
    k3_em<<<4370, 256, 0, stream>>>(W_fc, b_fc, ws);
    k4_bin<<<128, 256, 0, stream>>>(W_bin, b_bin, ws, out);
    k5_vit<<<128, 64, 0, stream>>>(masks, trans, startv, endv, ws, out);
}

// Round 12
// 6564.581 us; speedup vs baseline: 7.7189x; 1.4538x over previous
//
#include <hip/hip_runtime.h>
#include <math.h>

#define VOCAB 20000
#define EDIM  100
#define HDIM  200
#define KTAG  17
#define BATCH 128
#define TLEN  512

// ws layout (float offsets)
static const size_t PROJ_OFF = 0;              // 2 * 20000 * 800 = 32,000,000 floats
static const size_t LSTM_OFF = 32102464;       // 512*128*400 = 26,214,400
static const size_t EM_OFF   = 58316864;       // 512*128*17 = 1,114,112
// W2 (packed Whh, 80,000 float4 = 320,000 floats) overlaps the EM region:
// written by k0, read by k2, dead once k3 overwrites em.
// total = 59,430,976 floats = 237,723,904 bytes

// ---------------- K0: pack Whh — PROVEN L2-friendly layout (R6/R7) ----------------
// W2f4[d][k4][e][g] = Whh_d[row = g*200+e][k = 4*k4 .. 4*k4+3], k4 in [0,50)
// Lane-pair (e, gp) reads 32B of e's 64B line as 2 sectored 16B loads ->
// L2-resident (R6/R7: 206MB FETCH). Fully-coalesced [g][e] (R8) caused 14GB
// HBM refetch. Keep [e][g].
__global__ __launch_bounds__(256) void k0_pack(const float* __restrict__ Whh_f,
                                               const float* __restrict__ Whh_b,
                                               float* __restrict__ ws)
{
    int i = blockIdx.x * 256 + threadIdx.x;
    if (i >= 80000) return;
    int d = i / 40000, r = i % 40000;
    int k4 = r / 800, r2 = r % 800;
    int e = r2 >> 2, g = r2 & 3;
    const float* W = d ? Whh_b : Whh_f;
    float4 v = *(const float4*)(W + (size_t)(g * 200 + e) * 200 + 4 * k4);
    ((float4*)(ws + EM_OFF))[i] = v;
}

// ---------------- K1: per-vocab input projections ----------------
__global__ __launch_bounds__(256) void k1_proj(const float* __restrict__ emb,
                                               const float* __restrict__ Wf,
                                               const float* __restrict__ Wb,
                                               float* __restrict__ ws)
{
    int blk = blockIdx.x;
    int d = blk / 313, vt = blk % 313;
    const float* Wih = d ? Wb : Wf;
    float* proj = ws + PROJ_OFF + (size_t)d * VOCAB * 800;
    __shared__ float elds[64][104];
    __shared__ float olds[64][4][26];
    int tid = threadIdx.x;
    for (int idx = tid; idx < 64 * EDIM; idx += 256) {
        int r = idx / EDIM, c = idx % EDIM;
        int v = vt * 64 + r;
        elds[r][c] = (v < VOCAB) ? emb[(size_t)v * EDIM + c] : 0.f;
    }
    __syncthreads();
    int lane = tid & 63, wq = tid >> 6;
    float4 er[25];
#pragma unroll
    for (int i = 0; i < 25; i++) er[i] = *(const float4*)&elds[lane][4 * i];
#pragma unroll 1
    for (int round = 0; round < 8; round++) {
#pragma unroll 1
        for (int m = 0; m < 25; m++) {
            int oj = wq * 200 + round * 25 + m;      // wave-uniform
            int e = oj >> 2, g = oj & 3;
            int row = __builtin_amdgcn_readfirstlane(g * HDIM + e);
            const float* wrow = Wih + (size_t)row * EDIM;
            float acc = 0.f;
#pragma unroll
            for (int i = 0; i < 25; i++) {
                float4 w4 = *(const float4*)&wrow[4 * i];
                acc += w4.x * er[i].x + w4.y * er[i].y + w4.z * er[i].z + w4.w * er[i].w;
            }
            olds[lane][wq][m] = acc;
        }
        __syncthreads();
        for (int idx = tid; idx < 6400; idx += 256) {
            int vloc = idx / 100, rem = idx % 100;
            int q = rem / 25, c = rem % 25;
            int vv = vt * 64 + vloc;
            if (vv < VOCAB) proj[(size_t)vv * 800 + q * 200 + round * 25 + c] = olds[vloc][q][c];
        }
        __syncthreads();
    }
}

// ---------------- K2: bidirectional LSTM, gate-split pairing ----------------
// R11 redesign: thread (te = tid>>1, gp = tid&1) computes 2 gates (gp0: i,f;
// gp1: g,o) over the FULL k=200 for 4 batches. Lane pairs sit 32B apart in the
// same [e][g] line -> each wave load instruction touches 32 lines (vs 64) and
// there are 2 instructions per k4-group (vs 4): TA lookups/CU/step HALVE
// (R6/R11 evidence: the per-CU W-path queue is the floor, TLP doesn't help).
// No k-split reduction: gates combine via one __shfl_xor pair exchange; ONE
// barrier per step. Envelope = R6's proven (512,2): 68-VGPR precedent, no spill.
__global__ __launch_bounds__(512, 2) void k2_lstm(const int* __restrict__ sentence,
                                                  const float* __restrict__ bf,
                                                  const float* __restrict__ bb,
                                                  float* __restrict__ ws)
{
    int w = blockIdx.x;               // 64 = 2 dirs x 16... (2 x 32 tiles, B=4)
    int d = w >> 5, bt = w & 31;
    int B0 = bt * 4;
    const float* bvec = d ? bb : bf;
    const float* proj = ws + PROJ_OFF + (size_t)d * VOCAB * 800;
    const float4* W2 = (const float4*)(ws + EM_OFF) + (size_t)d * 40000;
    float* lstm_out = ws + LSTM_OFF;

    __shared__ float h_lds[2][4][208];   // 6656 B, double-buffered
    __shared__ int   tok[4][TLEN];       // 8192 B

    int tid = threadIdx.x;
    int te = tid >> 1, gp = tid & 1;
    bool active = te < 200;

#pragma unroll
    for (int b = 0; b < 4; b++)
        tok[b][tid] = sentence[(size_t)(B0 + b) * TLEN + tid];
    for (int i = tid; i < 4 * 208; i += 512) ((float*)h_lds[0])[i] = 0.f;

    float bias_i = 0.f, bias_f = 0.f, bias_g = 0.f, bias_o = 0.f;
    if (gp == 0 && active) {
        bias_i = bvec[te];
        bias_f = bvec[200 + te];
        bias_g = bvec[400 + te];
        bias_o = bvec[600 + te];
    }
    // W2 float4 index: (k4*200 + e)*4 + g ; this thread reads g = 2*gp, 2*gp+1
    const float4* wbase = W2 + ((size_t)(active ? te : 0)) * 4 + gp * 2;
    float c_st[4];
#pragma unroll
    for (int b = 0; b < 4; b++) c_st[b] = 0.f;
    __syncthreads();

#pragma unroll 1
    for (int t = 0; t < TLEN; t++) {
        int t_eff = d ? (TLEN - 1 - t) : t;
        int p = t & 1;

        // xp gathers: issued at step top, consumed in the epilogue
        float4 xp[4];
        if (gp == 0 && active) {
#pragma unroll
            for (int b = 0; b < 4; b++)
                xp[b] = *(const float4*)(proj + (size_t)tok[b][t_eff] * 800 + 4 * te);
        }

        float acc[2][4];                 // [gate-of-pair][batch]
#pragma unroll
        for (int g = 0; g < 2; g++)
#pragma unroll
            for (int b = 0; b < 4; b++) acc[g][b] = 0.f;

        if (active) {
            // 2-stream (A=even, B=odd k4-groups), 2-deep W register pipeline.
            // h comes from LDS per group: wave-uniform address = broadcast, free.
            float4 wA0, wA1, wB0, wB1, hv[4];
            const float4* wpA = wbase;               // groups 0,2,4,...
            const float4* wpB = wbase + 800;         // groups 1,3,5,...
            wA0 = wpA[0]; wA1 = wpA[1];
            wB0 = wpB[0]; wB1 = wpB[1];
#define K2_STEP(W0, W1, J)                                                        \
            {                                                                     \
                _Pragma("unroll")                                                 \
                for (int b = 0; b < 4; b++)                                       \
                    hv[b] = *(const float4*)&h_lds[p][b][4 * (J)];                \
                _Pragma("unroll")                                                 \
                for (int b = 0; b < 4; b++) {                                     \
                    float4 H = hv[b];                                             \
                    acc[0][b] += W0.x*H.x + W0.y*H.y + W0.z*H.z + W0.w*H.w;       \
                    acc[1][b] += W1.x*H.x + W1.y*H.y + W1.z*H.z + W1.w*H.w;       \
                }                                                                 \
            }
#define K2_PREF(W0, W1, WP, J)                                                    \
            if ((J) < 50) {                                                       \
                WP += 1600;                                                       \
                W0 = WP[0]; W1 = WP[1];                                           \
            }
#pragma unroll 1
            for (int jp = 0; jp < 25; jp++) {
                int j0 = 2 * jp;
                K2_STEP(wA0, wA1, j0)
                K2_PREF(wA0, wA1, wpA, j0 + 2)
                K2_STEP(wB0, wB1, j0 + 1)
                K2_PREF(wB0, wB1, wpB, j0 + 3)
            }
#undef K2_STEP
#undef K2_PREF
        }

        // pair exchange: gp0 receives (aG, aO) from its gp1 neighbor (lane+1)
        float xg[4], xo[4];
#pragma unroll
        for (int b = 0; b < 4; b++) {
            xg[b] = __shfl_xor(acc[0][b], 1);
            xo[b] = __shfl_xor(acc[1][b], 1);
        }

        if (gp == 0 && active) {
            int pn = p ^ 1;
#pragma unroll
            for (int b = 0; b < 4; b++) {
                float gi = acc[0][b] + xp[b].x + bias_i;
                float gf = acc[1][b] + xp[b].y + bias_f;
                float gg = xg[b]     + xp[b].z + bias_g;
                float go = xo[b]     + xp[b].w + bias_o;
                float sI = 1.f / (1.f + expf(-gi));
                float sF = 1.f / (1.f + expf(-gf));
                float sO = 1.f / (1.f + expf(-go));
                c_st[b] = sF * c_st[b] + sI * tanhf(gg);
                float hv2 = sO * tanhf(c_st[b]);
                h_lds[pn][b][te] = hv2;
                lstm_out[((size_t)t_eff * BATCH + B0 + b) * 400 + d * 200 + te] = hv2;
            }
        }
        __syncthreads();   // step t's h-writes visible before step t+1's reads
    }
}

// ---------------- K3: emissions em = lstm_out @ W_fc^T + b_fc ----------------
__global__ __launch_bounds__(256) void k3_em(const float* __restrict__ Wfc,
                                             const float* __restrict__ bfc,
                                             float* __restrict__ ws)
{
    __shared__ float llds[15][404];
    __shared__ float wlds[17][404];
    const float* lstm = ws + LSTM_OFF;
    float* em = ws + EM_OFF;
    int n0 = blockIdx.x * 15;
    int tid = threadIdx.x;
    for (int idx = tid; idx < 15 * 400; idx += 256) {
        int r = idx / 400, c = idx % 400;
        int n = n0 + r;
        llds[r][c] = (n < BATCH * TLEN) ? lstm[(size_t)n * 400 + c] : 0.f;
    }
    for (int idx = tid; idx < 17 * 400; idx += 256) {
        int r = idx / 400, c = idx % 400;
        wlds[r][c] = Wfc[r * 400 + c];
    }
    __syncthreads();
    if (tid < 255) {
        int tk = tid / 17, k = tid % 17;
        int n = n0 + tk;
        if (n < BATCH * TLEN) {
            float acc = 0.f;
#pragma unroll
            for (int i = 0; i < 100; i++) {
                float4 a  = *(const float4*)&llds[tk][4 * i];
                float4 wv = *(const float4*)&wlds[k][4 * i];
                acc += a.x * wv.x + a.y * wv.y + a.z * wv.z + a.w * wv.w;
            }
            em[(size_t)n * KTAG + k] = acc + bfc[k];
        }
    }
}

// ---------------- K4: bin_scores = mean_t(lstm_out) @ W_bin^T + b_bin ----------------
__global__ __launch_bounds__(256) void k4_bin(const float* __restrict__ Wbin,
                                              const float* __restrict__ bbin,
                                              float* __restrict__ ws,
                                              float* __restrict__ out)
{
    int b = blockIdx.x, tid = threadIdx.x;
    const float* lstm = ws + LSTM_OFF;
    __shared__ float m_lds[400];
    float a0 = 0.f, a1 = 0.f;
#pragma unroll 4
    for (int t = 0; t < TLEN; t++) {
        const float* rowp = lstm + ((size_t)t * BATCH + b) * 400;
        a0 += rowp[tid];
        if (tid < 144) a1 += rowp[256 + tid];
    }
    m_lds[tid] = a0 * (1.f / 512.f);
    if (tid < 144) m_lds[256 + tid] = a1 * (1.f / 512.f);
    __syncthreads();
    int wv = tid >> 6, lane = tid & 63;
    if (wv < 2) {
        float p = 0.f;
        for (int j = lane; j < 400; j += 64) p += m_lds[j] * Wbin[wv * 400 + j];
#pragma unroll
        for (int off = 32; off > 0; off >>= 1) p += __shfl_down(p, off);
        if (lane == 0) out[(size_t)BATCH * TLEN + b * 2 + wv] = p + bbin[wv];
    }
}

// ---------------- K5: masked Viterbi decode + traceback ----------------
__global__ __launch_bounds__(64) void k5_vit(const int* __restrict__ masks,
                                             const float* __restrict__ trans,
                                             const float* __restrict__ startv,
                                             const float* __restrict__ endv,
                                             const float* __restrict__ ws,
                                             float* __restrict__ out)
{
    int b = blockIdx.x, lane = threadIdx.x;
    const float* em = ws + EM_OFF;
    __shared__ float emlds[TLEN * KTAG];
    __shared__ unsigned char bpl[TLEN * KTAG];
    __shared__ int mlds[TLEN];
    __shared__ unsigned char tagl[TLEN];
    __shared__ float slds[KTAG];
    __shared__ float fin[KTAG];

    for (int idx = lane; idx < TLEN * KTAG; idx += 64) {
        int tt = idx / KTAG, j = idx - tt * KTAG;
        emlds[idx] = em[((size_t)tt * BATCH + b) * KTAG + j];
    }
    for (int idx = lane; idx < TLEN; idx += 64) mlds[idx] = masks[(size_t)b * TLEN + idx];
    bool on = lane < KTAG;
    float tr[KTAG];
    if (on) {
#pragma unroll
        for (int i = 0; i < KTAG; i++) tr[i] = trans[i * KTAG + lane];
    }
    __syncthreads();
    float sown = 0.f;
    if (on) { sown = startv[lane] + emlds[lane]; slds[lane] = sown; }
    __syncthreads();
#pragma unroll 1
    for (int t = 1; t < TLEN; t++) {
        int m = mlds[t];
        float ns = sown; int idx = lane;
        if (on) {
            float best = -3.4e38f; int bi = 0;
#pragma unroll
            for (int i = 0; i < KTAG; i++) {
                float vv = slds[i] + tr[i];
                if (vv > best) { best = vv; bi = i; }   // strict > => first max (matches jnp.argmax)
            }
            if (m != 0) { ns = best + emlds[t * KTAG + lane]; idx = bi; }
        }
        __syncthreads();
        if (on) { sown = ns; slds[lane] = ns; bpl[t * KTAG + lane] = (unsigned char)idx; }
        __syncthreads();
    }
    if (on) fin[lane] = sown + endv[lane];
    __syncthreads();
    if (lane == 0) {
        float bb = -3.4e38f; int bi = 0;
#pragma unroll
        for (int i = 0; i < KTAG; i++) if (fin[i] > bb) { bb = fin[i]; bi = i; }
        int cur = bi;
        tagl[TLEN - 1] = (unsigned char)cur;
        for (int t = TLEN - 1; t >= 1; t--) {
            cur = bpl[t * KTAG + cur];
            tagl[t - 1] = (unsigned char)cur;
        }
    }
    __syncthreads();
    for (int s = lane; s < TLEN; s += 64) out[(size_t)b * TLEN + s] = (float)tagl[s];
}

extern "C" void kernel_launch(void* const* d_in, const int* in_sizes, int n_in,
                              void* d_out, int out_size, void* d_ws, size_t ws_size,
                              hipStream_t stream)
{
    (void)in_sizes; (void)n_in; (void)out_size; (void)ws_size;
    const int*   sentence = (const int*)d_in[0];
    const int*   masks    = (const int*)d_in[1];
    const float* emb      = (const float*)d_in[2];
    const float* Wih_f    = (const float*)d_in[3];
    const float* Whh_f    = (const float*)d_in[4];
    const float* b_f      = (const float*)d_in[5];
    const float* Wih_b    = (const float*)d_in[6];
    const float* Whh_b    = (const float*)d_in[7];
    const float* b_b      = (const float*)d_in[8];
    const float* W_fc     = (const float*)d_in[9];
    const float* b_fc     = (const float*)d_in[10];
    const float* W_bin    = (const float*)d_in[11];
    const float* b_bin    = (const float*)d_in[12];
    const float* trans    = (const float*)d_in[13];
    const float* startv   = (const float*)d_in[14];
    const float* endv     = (const float*)d_in[15];
    float* ws  = (float*)d_ws;
    float* out = (float*)d_out;

    k0_pack<<<313, 256, 0, stream>>>(Whh_f, Whh_b, ws);
    k1_proj<<<626, 256, 0, stream>>>(emb, Wih_f, Wih_b, ws);
    k2_lstm<<<64, 512, 0, stream>>>(sentence, b_f, b_b, ws);
    k3_em<<<4370, 256, 0, stream>>>(W_fc, b_fc, ws);
    k4_bin<<<128, 256, 0, stream>>>(W_bin, b_bin, ws, out);
    k5_vit<<<128, 64, 0, stream>>>(masks, trans, startv, endv, ws, out);
}

// Round 14
// 6308.259 us; speedup vs baseline: 8.0325x; 1.0406x over previous
//
#include <hip/hip_runtime.h>
#include <math.h>

#define VOCAB 20000
#define EDIM  100
#define HDIM  200
#define KTAG  17
#define BATCH 128
#define TLEN  512

// ws layout (float offsets)
static const size_t PROJ_OFF = 0;              // 2 * 20000 * 800 = 32,000,000 floats
static const size_t LSTM_OFF = 32102464;       // 512*128*400 = 26,214,400
static const size_t EM_OFF   = 58316864;       // 512*128*17 = 1,114,112
// W2 (packed Whh, 80,000 float4 = 320,000 floats) overlaps the EM region:
// written by k0, read by k2, dead once k3 overwrites em.
// total = 59,430,976 floats = 237,723,904 bytes

// ---------------- K0: pack Whh — PROVEN L2-friendly layout (R6/R7/R12) ----------------
// W2f4[d][k4][e][g] = Whh_d[row = g*200+e][k = 4*k4 .. 4*k4+3], k4 in [0,50)
// Lane (e, gp) reads 32B of e's 64B line as 2 sectored 16B loads -> L2-resident
// (206MB FETCH measured). Fully-coalesced [g][e] (R8) caused 14GB HBM refetch.
__global__ __launch_bounds__(256) void k0_pack(const float* __restrict__ Whh_f,
                                               const float* __restrict__ Whh_b,
                                               float* __restrict__ ws)
{
    int i = blockIdx.x * 256 + threadIdx.x;
    if (i >= 80000) return;
    int d = i / 40000, r = i % 40000;
    int k4 = r / 800, r2 = r % 800;
    int e = r2 >> 2, g = r2 & 3;
    const float* W = d ? Whh_b : Whh_f;
    float4 v = *(const float4*)(W + (size_t)(g * 200 + e) * 200 + 4 * k4);
    ((float4*)(ws + EM_OFF))[i] = v;
}

// ---------------- K1: per-vocab input projections ----------------
__global__ __launch_bounds__(256) void k1_proj(const float* __restrict__ emb,
                                               const float* __restrict__ Wf,
                                               const float* __restrict__ Wb,
                                               float* __restrict__ ws)
{
    int blk = blockIdx.x;
    int d = blk / 313, vt = blk % 313;
    const float* Wih = d ? Wb : Wf;
    float* proj = ws + PROJ_OFF + (size_t)d * VOCAB * 800;
    __shared__ float elds[64][104];
    __shared__ float olds[64][4][26];
    int tid = threadIdx.x;
    for (int idx = tid; idx < 64 * EDIM; idx += 256) {
        int r = idx / EDIM, c = idx % EDIM;
        int v = vt * 64 + r;
        elds[r][c] = (v < VOCAB) ? emb[(size_t)v * EDIM + c] : 0.f;
    }
    __syncthreads();
    int lane = tid & 63, wq = tid >> 6;
    float4 er[25];
#pragma unroll
    for (int i = 0; i < 25; i++) er[i] = *(const float4*)&elds[lane][4 * i];
#pragma unroll 1
    for (int round = 0; round < 8; round++) {
#pragma unroll 1
        for (int m = 0; m < 25; m++) {
            int oj = wq * 200 + round * 25 + m;      // wave-uniform
            int e = oj >> 2, g = oj & 3;
            int row = __builtin_amdgcn_readfirstlane(g * HDIM + e);
            const float* wrow = Wih + (size_t)row * EDIM;
            float acc = 0.f;
#pragma unroll
            for (int i = 0; i < 25; i++) {
                float4 w4 = *(const float4*)&wrow[4 * i];
                acc += w4.x * er[i].x + w4.y * er[i].y + w4.z * er[i].z + w4.w * er[i].w;
            }
            olds[lane][wq][m] = acc;
        }
        __syncthreads();
        for (int idx = tid; idx < 6400; idx += 256) {
            int vloc = idx / 100, rem = idx % 100;
            int q = rem / 25, c = rem % 25;
            int vv = vt * 64 + vloc;
            if (vv < VOCAB) proj[(size_t)vv * 800 + q * 200 + round * 25 + c] = olds[vloc][q][c];
        }
        __syncthreads();
    }
}

// ---------------- K2: bidirectional LSTM — C-level 5-deep W ring ----------------
// R13 post-mortem: the inline-asm ring crashed (compiler-invisible in-flight
// loads can be spilled/moved between asm blocks -> UB). Same pipeline idea in
// PURE C: 5 groups (10 loads) preloaded into NAMED registers (rule #20), each
// consume followed by a re-issue. The compiler's own waitcnt insertion is
// precise/counted (m131, r109 evidence), so this gets ~10 loads in flight per
// wave with zero correctness hazard. Tests the latency x concurrency theory of
// the 11.4us/step floor (R6/R7/R12 invariant: 640 KB W per CU per step at
// ~56 GB/s effective; Little's law at 300cyc L2 latency says depth ~2 is the
// binding constraint at 2 waves/SIMD).
// Mapping unchanged from R12: thread (te=tid>>1, gp=tid&1), 2 gates, k=200, B=4.
#define RING_LOAD(WA, WB) { WA = wp[0]; WB = wp[1]; wp += 800; }

#define RING_FMA(WA, WB, J)                                                   \
    {                                                                         \
        const float* hb = hrow + 4 * (J);                                     \
        float4 H0 = *(const float4*)(hb);                                     \
        float4 H1 = *(const float4*)(hb + 208);                               \
        float4 H2 = *(const float4*)(hb + 416);                               \
        float4 H3 = *(const float4*)(hb + 624);                               \
        a00 += WA.x*H0.x + WA.y*H0.y + WA.z*H0.z + WA.w*H0.w;                 \
        a01 += WA.x*H1.x + WA.y*H1.y + WA.z*H1.z + WA.w*H1.w;                 \
        a02 += WA.x*H2.x + WA.y*H2.y + WA.z*H2.z + WA.w*H2.w;                 \
        a03 += WA.x*H3.x + WA.y*H3.y + WA.z*H3.z + WA.w*H3.w;                 \
        a10 += WB.x*H0.x + WB.y*H0.y + WB.z*H0.z + WB.w*H0.w;                 \
        a11 += WB.x*H1.x + WB.y*H1.y + WB.z*H1.z + WB.w*H1.w;                 \
        a12 += WB.x*H2.x + WB.y*H2.y + WB.z*H2.z + WB.w*H2.w;                 \
        a13 += WB.x*H3.x + WB.y*H3.y + WB.z*H3.z + WB.w*H3.w;                 \
    }

__global__ __launch_bounds__(512, 2) void k2_lstm(const int* __restrict__ sentence,
                                                  const float* __restrict__ bf,
                                                  const float* __restrict__ bb,
                                                  float* __restrict__ ws)
{
    int w = blockIdx.x;               // 64 = 2 dirs x 32 batch-tiles (B=4)
    int d = w >> 5, bt = w & 31;
    int B0 = bt * 4;
    const float* bvec = d ? bb : bf;
    const float* proj = ws + PROJ_OFF + (size_t)d * VOCAB * 800;
    const float4* W2 = (const float4*)(ws + EM_OFF) + (size_t)d * 40000;
    float* lstm_out = ws + LSTM_OFF;

    __shared__ float h_lds[2][4][208];   // 6656 B, double-buffered
    __shared__ int   tok[4][TLEN];       // 8192 B

    int tid = threadIdx.x;
    int te = tid >> 1, gp = tid & 1;
    bool active = te < 200;

#pragma unroll
    for (int b = 0; b < 4; b++)
        tok[b][tid] = sentence[(size_t)(B0 + b) * TLEN + tid];
    for (int i = tid; i < 4 * 208; i += 512) ((float*)h_lds[0])[i] = 0.f;

    float bias_i = 0.f, bias_f = 0.f, bias_g = 0.f, bias_o = 0.f;
    if (gp == 0 && active) {
        bias_i = bvec[te];
        bias_f = bvec[200 + te];
        bias_g = bvec[400 + te];
        bias_o = bvec[600 + te];
    }
    // W2 float4 index: (k4*200 + e)*4 + g ; this thread reads g = 2*gp, 2*gp+1
    const float4* wbase = W2 + ((size_t)(active ? te : 0)) * 4 + gp * 2;
    float c0 = 0.f, c1 = 0.f, c2 = 0.f, c3 = 0.f;
    __syncthreads();

#pragma unroll 1
    for (int t = 0; t < TLEN; t++) {
        int t_eff = d ? (TLEN - 1 - t) : t;
        int p = t & 1;

        // xp gathers: issued at step top, consumed in the epilogue
        float4 xp0, xp1, xp2, xp3;
        if (gp == 0 && active) {
            xp0 = *(const float4*)(proj + (size_t)tok[0][t_eff] * 800 + 4 * te);
            xp1 = *(const float4*)(proj + (size_t)tok[1][t_eff] * 800 + 4 * te);
            xp2 = *(const float4*)(proj + (size_t)tok[2][t_eff] * 800 + 4 * te);
            xp3 = *(const float4*)(proj + (size_t)tok[3][t_eff] * 800 + 4 * te);
        }

        float a00 = 0.f, a01 = 0.f, a02 = 0.f, a03 = 0.f;
        float a10 = 0.f, a11 = 0.f, a12 = 0.f, a13 = 0.f;

        if (active) {
            const float* hrow = &h_lds[p][0][0];
            const float4* wp = wbase;
            float4 w0a, w0b, w1a, w1b, w2a, w2b, w3a, w3b, w4a, w4b;
            // preload ring: groups 0..4 (10 wave-loads in flight)
            RING_LOAD(w0a, w0b)
            RING_LOAD(w1a, w1b)
            RING_LOAD(w2a, w2b)
            RING_LOAD(w3a, w3b)
            RING_LOAD(w4a, w4b)
            // steady state: consume group j, re-issue group j+5 (compiler emits
            // the counted vmcnt waits; loads stay compiler-visible -> no R13 UB)
#pragma unroll 1
            for (int it = 0; it < 9; ++it) {
                int j0 = it * 5;
                RING_FMA(w0a, w0b, j0 + 0) RING_LOAD(w0a, w0b)
                RING_FMA(w1a, w1b, j0 + 1) RING_LOAD(w1a, w1b)
                RING_FMA(w2a, w2b, j0 + 2) RING_LOAD(w2a, w2b)
                RING_FMA(w3a, w3b, j0 + 3) RING_LOAD(w3a, w3b)
                RING_FMA(w4a, w4b, j0 + 4) RING_LOAD(w4a, w4b)
            }
            // tail: groups 45..49 (loaded during it=8), no re-issue
            RING_FMA(w0a, w0b, 45)
            RING_FMA(w1a, w1b, 46)
            RING_FMA(w2a, w2b, 47)
            RING_FMA(w3a, w3b, 48)
            RING_FMA(w4a, w4b, 49)
        }

        // pair exchange: gp0 receives (aG, aO) from its gp1 neighbor (lane+1)
        float xg0 = __shfl_xor(a00, 1), xg1 = __shfl_xor(a01, 1);
        float xg2 = __shfl_xor(a02, 1), xg3 = __shfl_xor(a03, 1);
        float xo0 = __shfl_xor(a10, 1), xo1 = __shfl_xor(a11, 1);
        float xo2 = __shfl_xor(a12, 1), xo3 = __shfl_xor(a13, 1);

        if (gp == 0 && active) {
            int pn = p ^ 1;
            float gi, gf, gg, go, sI, sF, sO, hv2;
            gi = a00 + xp0.x + bias_i;  gf = a10 + xp0.y + bias_f;
            gg = xg0 + xp0.z + bias_g;  go = xo0 + xp0.w + bias_o;
            sI = 1.f/(1.f+expf(-gi)); sF = 1.f/(1.f+expf(-gf)); sO = 1.f/(1.f+expf(-go));
            c0 = sF*c0 + sI*tanhf(gg);  hv2 = sO*tanhf(c0);
            h_lds[pn][0][te] = hv2;
            lstm_out[((size_t)t_eff * BATCH + B0 + 0) * 400 + d * 200 + te] = hv2;

            gi = a01 + xp1.x + bias_i;  gf = a11 + xp1.y + bias_f;
            gg = xg1 + xp1.z + bias_g;  go = xo1 + xp1.w + bias_o;
            sI = 1.f/(1.f+expf(-gi)); sF = 1.f/(1.f+expf(-gf)); sO = 1.f/(1.f+expf(-go));
            c1 = sF*c1 + sI*tanhf(gg);  hv2 = sO*tanhf(c1);
            h_lds[pn][1][te] = hv2;
            lstm_out[((size_t)t_eff * BATCH + B0 + 1) * 400 + d * 200 + te] = hv2;

            gi = a02 + xp2.x + bias_i;  gf = a12 + xp2.y + bias_f;
            gg = xg2 + xp2.z + bias_g;  go = xo2 + xp2.w + bias_o;
            sI = 1.f/(1.f+expf(-gi)); sF = 1.f/(1.f+expf(-gf)); sO = 1.f/(1.f+expf(-go));
            c2 = sF*c2 + sI*tanhf(gg);  hv2 = sO*tanhf(c2);
            h_lds[pn][2][te] = hv2;
            lstm_out[((size_t)t_eff * BATCH + B0 + 2) * 400 + d * 200 + te] = hv2;

            gi = a03 + xp3.x + bias_i;  gf = a13 + xp3.y + bias_f;
            gg = xg3 + xp3.z + bias_g;  go = xo3 + xp3.w + bias_o;
            sI = 1.f/(1.f+expf(-gi)); sF = 1.f/(1.f+expf(-gf)); sO = 1.f/(1.f+expf(-go));
            c3 = sF*c3 + sI*tanhf(gg);  hv2 = sO*tanhf(c3);
            h_lds[pn][3][te] = hv2;
            lstm_out[((size_t)t_eff * BATCH + B0 + 3) * 400 + d * 200 + te] = hv2;
        }
        __syncthreads();   // step t's h-writes visible before step t+1's reads
    }
}

// ---------------- K3: emissions em = lstm_out @ W_fc^T + b_fc ----------------
__global__ __launch_bounds__(256) void k3_em(const float* __restrict__ Wfc,
                                             const float* __restrict__ bfc,
                                             float* __restrict__ ws)
{
    __shared__ float llds[15][404];
    __shared__ float wlds[17][404];
    const float* lstm = ws + LSTM_OFF;
    float* em = ws + EM_OFF;
    int n0 = blockIdx.x * 15;
    int tid = threadIdx.x;
    for (int idx = tid; idx < 15 * 400; idx += 256) {
        int r = idx / 400, c = idx % 400;
        int n = n0 + r;
        llds[r][c] = (n < BATCH * TLEN) ? lstm[(size_t)n * 400 + c] : 0.f;
    }
    for (int idx = tid; idx < 17 * 400; idx += 256) {
        int r = idx / 400, c = idx % 400;
        wlds[r][c] = Wfc[r * 400 + c];
    }
    __syncthreads();
    if (tid < 255) {
        int tk = tid / 17, k = tid % 17;
        int n = n0 + tk;
        if (n < BATCH * TLEN) {
            float acc = 0.f;
#pragma unroll
            for (int i = 0; i < 100; i++) {
                float4 a  = *(const float4*)&llds[tk][4 * i];
                float4 wv = *(const float4*)&wlds[k][4 * i];
                acc += a.x * wv.x + a.y * wv.y + a.z * wv.z + a.w * wv.w;
            }
            em[(size_t)n * KTAG + k] = acc + bfc[k];
        }
    }
}

// ---------------- K4: bin_scores = mean_t(lstm_out) @ W_bin^T + b_bin ----------------
__global__ __launch_bounds__(256) void k4_bin(const float* __restrict__ Wbin,
                                              const float* __restrict__ bbin,
                                              float* __restrict__ ws,
                                              float* __restrict__ out)
{
    int b = blockIdx.x, tid = threadIdx.x;
    const float* lstm = ws + LSTM_OFF;
    __shared__ float m_lds[400];
    float a0 = 0.f, a1 = 0.f;
#pragma unroll 4
    for (int t = 0; t < TLEN; t++) {
        const float* rowp = lstm + ((size_t)t * BATCH + b) * 400;
        a0 += rowp[tid];
        if (tid < 144) a1 += rowp[256 + tid];
    }
    m_lds[tid] = a0 * (1.f / 512.f);
    if (tid < 144) m_lds[256 + tid] = a1 * (1.f / 512.f);
    __syncthreads();
    int wv = tid >> 6, lane = tid & 63;
    if (wv < 2) {
        float p = 0.f;
        for (int j = lane; j < 400; j += 64) p += m_lds[j] * Wbin[wv * 400 + j];
#pragma unroll
        for (int off = 32; off > 0; off >>= 1) p += __shfl_down(p, off);
        if (lane == 0) out[(size_t)BATCH * TLEN + b * 2 + wv] = p + bbin[wv];
    }
}

// ---------------- K5: masked Viterbi decode + traceback ----------------
__global__ __launch_bounds__(64) void k5_vit(const int* __restrict__ masks,
                                             const float* __restrict__ trans,
                                             const float* __restrict__ startv,
                                             const float* __restrict__ endv,
                                             const float* __restrict__ ws,
                                             float* __restrict__ out)
{
    int b = blockIdx.x, lane = threadIdx.x;
    const float* em = ws + EM_OFF;
    __shared__ float emlds[TLEN * KTAG];
    __shared__ unsigned char bpl[TLEN * KTAG];
    __shared__ int mlds[TLEN];
    __shared__ unsigned char tagl[TLEN];
    __shared__ float slds[KTAG];
    __shared__ float fin[KTAG];

    for (int idx = lane; idx < TLEN * KTAG; idx += 64) {
        int tt = idx / KTAG, j = idx - tt * KTAG;
        emlds[idx] = em[((size_t)tt * BATCH + b) * KTAG + j];
    }
    for (int idx = lane; idx < TLEN; idx += 64) mlds[idx] = masks[(size_t)b * TLEN + idx];
    bool on = lane < KTAG;
    float tr[KTAG];
    if (on) {
#pragma unroll
        for (int i = 0; i < KTAG; i++) tr[i] = trans[i * KTAG + lane];
    }
    __syncthreads();
    float sown = 0.f;
    if (on) { sown = startv[lane] + emlds[lane]; slds[lane] = sown; }
    __syncthreads();
#pragma unroll 1
    for (int t = 1; t < TLEN; t++) {
        int m = mlds[t];
        float ns = sown; int idx = lane;
        if (on) {
            float best = -3.4e38f; int bi = 0;
#pragma unroll
            for (int i = 0; i < KTAG; i++) {
                float vv = slds[i] + tr[i];
                if (vv > best) { best = vv; bi = i; }   // strict > => first max (matches jnp.argmax)
            }
            if (m != 0) { ns = best + emlds[t * KTAG + lane]; idx = bi; }
        }
        __syncthreads();
        if (on) { sown = ns; slds[lane] = ns; bpl[t * KTAG + lane] = (unsigned char)idx; }
        __syncthreads();
    }
    if (on) fin[lane] = sown + endv[lane];
    __syncthreads();
    if (lane == 0) {
        float bb = -3.4e38f; int bi = 0;
#pragma unroll
        for (int i = 0; i < KTAG; i++) if (fin[i] > bb) { bb = fin[i]; bi = i; }
        int cur = bi;
        tagl[TLEN - 1] = (unsigned char)cur;
        for (int t = TLEN - 1; t >= 1; t--) {
            cur = bpl[t * KTAG + cur];
            tagl[t - 1] = (unsigned char)cur;
        }
    }
    __syncthreads();
    for (int s = lane; s < TLEN; s += 64) out[(size_t)b * TLEN + s] = (float)tagl[s];
}

extern "C" void kernel_launch(void* const* d_in, const int* in_sizes, int n_in,
                              void* d_out, int out_size, void* d_ws, size_t ws_size,
                              hipStream_t stream)
{
    (void)in_sizes; (void)n_in; (void)out_size; (void)ws_size;
    const int*   sentence = (const int*)d_in[0];
    const int*   masks    = (const int*)d_in[1];
    const float* emb      = (const float*)d_in[2];
    const float* Wih_f    = (const float*)d_in[3];
    const float* Whh_f    = (const float*)d_in[4];
    const float* b_f      = (const float*)d_in[5];
    const float* Wih_b    = (const float*)d_in[6];
    const float* Whh_b    = (const float*)d_in[7];
    const float* b_b      = (const float*)d_in[8];
    const float* W_fc     = (const float*)d_in[9];
    const float* b_fc     = (const float*)d_in[10];
    const float* W_bin    = (const float*)d_in[11];
    const float* b_bin    = (const float*)d_in[12];
    const float* trans    = (const float*)d_in[13];
    const float* startv   = (const float*)d_in[14];
    const float* endv     = (const float*)d_in[15];
    float* ws  = (float*)d_ws;
    float* out = (float*)d_out;

    k0_pack<<<313, 256, 0, stream>>>(Whh_f, Whh_b, ws);
    k1_proj<<<626, 256, 0, stream>>>(emb, Wih_f, Wih_b, ws);
    k2_lstm<<<64, 512, 0, stream>>>(sentence, b_f, b_b, ws);
    k3_em<<<4370, 256, 0, stream>>>(W_fc, b_fc, ws);
    k4_bin<<<128, 256, 0, stream>>>(W_bin, b_bin, ws, out);
    k5_vit<<<128, 64, 0, stream>>>(masks, trans, startv, endv, ws, out);
}

// Round 15
// 6014.046 us; speedup vs baseline: 8.4255x; 1.0489x over previous
//
#include <hip/hip_runtime.h>
#include <math.h>

#define VOCAB 20000
#define EDIM  100
#define HDIM  200
#define KTAG  17
#define BATCH 128
#define TLEN  512

// ws layout (float offsets)
static const size_t PROJ_OFF = 0;              // 2 * 20000 * 800 = 32,000,000 floats
static const size_t LSTM_OFF = 32102464;       // 512*128*400 = 26,214,400
static const size_t EM_OFF   = 58316864;       // 512*128*17 = 1,114,112
// W2 (packed Whh, 80,000 float4 = 320,000 floats) overlaps the EM region:
// written by k0, read by k2, dead once k3 overwrites em.
// total = 59,430,976 floats = 237,723,904 bytes

// ---------------- K0: pack Whh — PROVEN L2-friendly layout (R6/R7/R12) ----------------
// W2f4[d][k4][e][g] = Whh_d[row = g*200+e][k = 4*k4 .. 4*k4+3], k4 in [0,50)
// Lane (e, gp) reads 32B of e's 64B line as 2 sectored 16B loads -> L2-resident
// (206MB FETCH measured). Fully-coalesced [g][e] (R8) caused 14GB HBM refetch.
__global__ __launch_bounds__(256) void k0_pack(const float* __restrict__ Whh_f,
                                               const float* __restrict__ Whh_b,
                                               float* __restrict__ ws)
{
    int i = blockIdx.x * 256 + threadIdx.x;
    if (i >= 80000) return;
    int d = i / 40000, r = i % 40000;
    int k4 = r / 800, r2 = r % 800;
    int e = r2 >> 2, g = r2 & 3;
    const float* W = d ? Whh_b : Whh_f;
    float4 v = *(const float4*)(W + (size_t)(g * 200 + e) * 200 + 4 * k4);
    ((float4*)(ws + EM_OFF))[i] = v;
}

// ---------------- K1: per-vocab input projections ----------------
__global__ __launch_bounds__(256) void k1_proj(const float* __restrict__ emb,
                                               const float* __restrict__ Wf,
                                               const float* __restrict__ Wb,
                                               float* __restrict__ ws)
{
    int blk = blockIdx.x;
    int d = blk / 313, vt = blk % 313;
    const float* Wih = d ? Wb : Wf;
    float* proj = ws + PROJ_OFF + (size_t)d * VOCAB * 800;
    __shared__ float elds[64][104];
    __shared__ float olds[64][4][26];
    int tid = threadIdx.x;
    for (int idx = tid; idx < 64 * EDIM; idx += 256) {
        int r = idx / EDIM, c = idx % EDIM;
        int v = vt * 64 + r;
        elds[r][c] = (v < VOCAB) ? emb[(size_t)v * EDIM + c] : 0.f;
    }
    __syncthreads();
    int lane = tid & 63, wq = tid >> 6;
    float4 er[25];
#pragma unroll
    for (int i = 0; i < 25; i++) er[i] = *(const float4*)&elds[lane][4 * i];
#pragma unroll 1
    for (int round = 0; round < 8; round++) {
#pragma unroll 1
        for (int m = 0; m < 25; m++) {
            int oj = wq * 200 + round * 25 + m;      // wave-uniform
            int e = oj >> 2, g = oj & 3;
            int row = __builtin_amdgcn_readfirstlane(g * HDIM + e);
            const float* wrow = Wih + (size_t)row * EDIM;
            float acc = 0.f;
#pragma unroll
            for (int i = 0; i < 25; i++) {
                float4 w4 = *(const float4*)&wrow[4 * i];
                acc += w4.x * er[i].x + w4.y * er[i].y + w4.z * er[i].z + w4.w * er[i].w;
            }
            olds[lane][wq][m] = acc;
        }
        __syncthreads();
        for (int idx = tid; idx < 6400; idx += 256) {
            int vloc = idx / 100, rem = idx % 100;
            int q = rem / 25, c = rem % 25;
            int vv = vt * 64 + vloc;
            if (vv < VOCAB) proj[(size_t)vv * 800 + q * 200 + round * 25 + c] = olds[vloc][q][c];
        }
        __syncthreads();
    }
}

// ---------------- K2: bidirectional LSTM — W residency + streamed ring ----------------
// R14 established the floor: ~57 GB/s/CU L2 streaming across 5 access shapes ->
// time/step ~ bytes/57GB/s + ~2us fixed. This round reduces BYTES: groups 0-4
// (40 VGPR) and 5-8 (51.2 KB LDS) of W are resident on-CU; only groups 9-49
// (41/50 = 525 KB) stream per step via the proven C-level ring. Ring preload
// issues FIRST so its latency hides under the 9 resident-group FMAs.
// Mapping unchanged: thread (te=tid>>1, gp=tid&1), 2 gates, k=200, B=4.
#define RING_LOAD(WA, WB) { WA = wp[0]; WB = wp[1]; wp += 800; }

#define RING_FMA(WA, WB, J)                                                   \
    {                                                                         \
        const float* hb = hrow + 4 * (J);                                     \
        float4 H0 = *(const float4*)(hb);                                     \
        float4 H1 = *(const float4*)(hb + 208);                               \
        float4 H2 = *(const float4*)(hb + 416);                               \
        float4 H3 = *(const float4*)(hb + 624);                               \
        a00 += WA.x*H0.x + WA.y*H0.y + WA.z*H0.z + WA.w*H0.w;                 \
        a01 += WA.x*H1.x + WA.y*H1.y + WA.z*H1.z + WA.w*H1.w;                 \
        a02 += WA.x*H2.x + WA.y*H2.y + WA.z*H2.z + WA.w*H2.w;                 \
        a03 += WA.x*H3.x + WA.y*H3.y + WA.z*H3.z + WA.w*H3.w;                 \
        a10 += WB.x*H0.x + WB.y*H0.y + WB.z*H0.z + WB.w*H0.w;                 \
        a11 += WB.x*H1.x + WB.y*H1.y + WB.z*H1.z + WB.w*H1.w;                 \
        a12 += WB.x*H2.x + WB.y*H2.y + WB.z*H2.z + WB.w*H2.w;                 \
        a13 += WB.x*H3.x + WB.y*H3.y + WB.z*H3.z + WB.w*H3.w;                 \
    }

__global__ __launch_bounds__(512, 2) void k2_lstm(const int* __restrict__ sentence,
                                                  const float* __restrict__ bf,
                                                  const float* __restrict__ bb,
                                                  float* __restrict__ ws)
{
    int w = blockIdx.x;               // 64 = 2 dirs x 32 batch-tiles (B=4)
    int d = w >> 5, bt = w & 31;
    int B0 = bt * 4;
    const float* bvec = d ? bb : bf;
    const float* proj = ws + PROJ_OFF + (size_t)d * VOCAB * 800;
    const float4* W2 = (const float4*)(ws + EM_OFF) + (size_t)d * 40000;
    float* lstm_out = ws + LSTM_OFF;

    __shared__ float4 w_sh[4][200][2][2];   // 51,200 B : W groups 5..8 resident
    __shared__ float h_lds[2][4][208];      //  6,656 B : h double-buffer
    // static LDS total 57,856 B (< 64 KB); tok table dropped (direct loads)

    int tid = threadIdx.x;
    int te = tid >> 1, gp = tid & 1;
    bool active = te < 200;

    // one-time: W groups 5..8 -> LDS (32B per thread, coalesced)
    for (int i = tid; i < 1600; i += 512) {
        int jj = i / 400, r = i % 400, te_ = r >> 1, gp_ = r & 1;
        const float4* src = W2 + ((size_t)(jj + 5) * 200 + te_) * 4 + gp_ * 2;
        w_sh[jj][te_][gp_][0] = src[0];
        w_sh[jj][te_][gp_][1] = src[1];
    }
    for (int i = tid; i < 4 * 208; i += 512) ((float*)h_lds[0])[i] = 0.f;

    float bias_i = 0.f, bias_f = 0.f, bias_g = 0.f, bias_o = 0.f;
    if (gp == 0 && active) {
        bias_i = bvec[te];
        bias_f = bvec[200 + te];
        bias_g = bvec[400 + te];
        bias_o = bvec[600 + te];
    }
    // W2 float4 index: (k4*200 + e)*4 + g ; this thread reads g = 2*gp, 2*gp+1
    const float4* wbase = W2 + ((size_t)(active ? te : 0)) * 4 + gp * 2;

    // one-time: W groups 0..4 resident in NAMED registers (40 VGPR)
    float4 r0a, r0b, r1a, r1b, r2a, r2b, r3a, r3b, r4a, r4b;
    {
        const float4* wp2 = wbase;
        r0a = wp2[0]; r0b = wp2[1]; wp2 += 800;
        r1a = wp2[0]; r1b = wp2[1]; wp2 += 800;
        r2a = wp2[0]; r2b = wp2[1]; wp2 += 800;
        r3a = wp2[0]; r3b = wp2[1]; wp2 += 800;
        r4a = wp2[0]; r4b = wp2[1];
    }
    float c0 = 0.f, c1 = 0.f, c2 = 0.f, c3 = 0.f;
    __syncthreads();

#pragma unroll 1
    for (int t = 0; t < TLEN; t++) {
        int t_eff = d ? (TLEN - 1 - t) : t;
        int p = t & 1;

        // xp gathers: token loads (same address per wave -> 1 line, L2-hot)
        // then proj gathers; issued at step top, consumed in the epilogue
        float4 xp0, xp1, xp2, xp3;
        if (gp == 0 && active) {
            int t0 = sentence[(size_t)(B0 + 0) * TLEN + t_eff];
            int t1 = sentence[(size_t)(B0 + 1) * TLEN + t_eff];
            int t2 = sentence[(size_t)(B0 + 2) * TLEN + t_eff];
            int t3 = sentence[(size_t)(B0 + 3) * TLEN + t_eff];
            xp0 = *(const float4*)(proj + (size_t)t0 * 800 + 4 * te);
            xp1 = *(const float4*)(proj + (size_t)t1 * 800 + 4 * te);
            xp2 = *(const float4*)(proj + (size_t)t2 * 800 + 4 * te);
            xp3 = *(const float4*)(proj + (size_t)t3 * 800 + 4 * te);
        }

        float a00 = 0.f, a01 = 0.f, a02 = 0.f, a03 = 0.f;
        float a10 = 0.f, a11 = 0.f, a12 = 0.f, a13 = 0.f;

        if (active) {
            const float* hrow = &h_lds[p][0][0];
            const float4* wp = wbase + 7200;     // streamed region starts at group 9
            float4 w0a, w0b, w1a, w1b, w2a, w2b, w3a, w3b, w4a, w4b;
            // issue the stream FIRST (latency hides under 9 resident consumes)
            RING_LOAD(w0a, w0b)                  // group 9
            RING_LOAD(w1a, w1b)                  // group 10
            RING_LOAD(w2a, w2b)                  // group 11
            RING_LOAD(w3a, w3b)                  // group 12
            RING_LOAD(w4a, w4b)                  // group 13
            // resident consumes: groups 0..4 from registers
            RING_FMA(r0a, r0b, 0)
            RING_FMA(r1a, r1b, 1)
            RING_FMA(r2a, r2b, 2)
            RING_FMA(r3a, r3b, 3)
            RING_FMA(r4a, r4b, 4)
            // resident consumes: groups 5..8 from LDS
            { float4 la = w_sh[0][te][gp][0], lb = w_sh[0][te][gp][1]; RING_FMA(la, lb, 5) }
            { float4 la = w_sh[1][te][gp][0], lb = w_sh[1][te][gp][1]; RING_FMA(la, lb, 6) }
            { float4 la = w_sh[2][te][gp][0], lb = w_sh[2][te][gp][1]; RING_FMA(la, lb, 7) }
            { float4 la = w_sh[3][te][gp][0], lb = w_sh[3][te][gp][1]; RING_FMA(la, lb, 8) }
            // streamed: groups 9..49 via 5-deep ring (named slots, rule #20)
#pragma unroll 1
            for (int it = 0; it < 7; ++it) {
                int j0 = 9 + it * 5;
                RING_FMA(w0a, w0b, j0 + 0) RING_LOAD(w0a, w0b)
                RING_FMA(w1a, w1b, j0 + 1) RING_LOAD(w1a, w1b)
                RING_FMA(w2a, w2b, j0 + 2) RING_LOAD(w2a, w2b)
                RING_FMA(w3a, w3b, j0 + 3) RING_LOAD(w3a, w3b)
                RING_FMA(w4a, w4b, j0 + 4) RING_LOAD(w4a, w4b)
            }
            // tail: slots hold groups 44..48; one last load (49) then drain
            RING_FMA(w0a, w0b, 44) RING_LOAD(w0a, w0b)   // loads group 49
            RING_FMA(w1a, w1b, 45)
            RING_FMA(w2a, w2b, 46)
            RING_FMA(w3a, w3b, 47)
            RING_FMA(w4a, w4b, 48)
            RING_FMA(w0a, w0b, 49)
        }

        // pair exchange: gp0 receives (aG, aO) from its gp1 neighbor (lane+1)
        float xg0 = __shfl_xor(a00, 1), xg1 = __shfl_xor(a01, 1);
        float xg2 = __shfl_xor(a02, 1), xg3 = __shfl_xor(a03, 1);
        float xo0 = __shfl_xor(a10, 1), xo1 = __shfl_xor(a11, 1);
        float xo2 = __shfl_xor(a12, 1), xo3 = __shfl_xor(a13, 1);

        if (gp == 0 && active) {
            int pn = p ^ 1;
            float gi, gf, gg, go, sI, sF, sO, hv2;
            gi = a00 + xp0.x + bias_i;  gf = a10 + xp0.y + bias_f;
            gg = xg0 + xp0.z + bias_g;  go = xo0 + xp0.w + bias_o;
            sI = 1.f/(1.f+expf(-gi)); sF = 1.f/(1.f+expf(-gf)); sO = 1.f/(1.f+expf(-go));
            c0 = sF*c0 + sI*tanhf(gg);  hv2 = sO*tanhf(c0);
            h_lds[pn][0][te] = hv2;
            lstm_out[((size_t)t_eff * BATCH + B0 + 0) * 400 + d * 200 + te] = hv2;

            gi = a01 + xp1.x + bias_i;  gf = a11 + xp1.y + bias_f;
            gg = xg1 + xp1.z + bias_g;  go = xo1 + xp1.w + bias_o;
            sI = 1.f/(1.f+expf(-gi)); sF = 1.f/(1.f+expf(-gf)); sO = 1.f/(1.f+expf(-go));
            c1 = sF*c1 + sI*tanhf(gg);  hv2 = sO*tanhf(c1);
            h_lds[pn][1][te] = hv2;
            lstm_out[((size_t)t_eff * BATCH + B0 + 1) * 400 + d * 200 + te] = hv2;

            gi = a02 + xp2.x + bias_i;  gf = a12 + xp2.y + bias_f;
            gg = xg2 + xp2.z + bias_g;  go = xo2 + xp2.w + bias_o;
            sI = 1.f/(1.f+expf(-gi)); sF = 1.f/(1.f+expf(-gf)); sO = 1.f/(1.f+expf(-go));
            c2 = sF*c2 + sI*tanhf(gg);  hv2 = sO*tanhf(c2);
            h_lds[pn][2][te] = hv2;
            lstm_out[((size_t)t_eff * BATCH + B0 + 2) * 400 + d * 200 + te] = hv2;

            gi = a03 + xp3.x + bias_i;  gf = a13 + xp3.y + bias_f;
            gg = xg3 + xp3.z + bias_g;  go = xo3 + xp3.w + bias_o;
            sI = 1.f/(1.f+expf(-gi)); sF = 1.f/(1.f+expf(-gf)); sO = 1.f/(1.f+expf(-go));
            c3 = sF*c3 + sI*tanhf(gg);  hv2 = sO*tanhf(c3);
            h_lds[pn][3][te] = hv2;
            lstm_out[((size_t)t_eff * BATCH + B0 + 3) * 400 + d * 200 + te] = hv2;
        }
        __syncthreads();   // step t's h-writes visible before step t+1's reads
    }
}

// ---------------- K3: emissions em = lstm_out @ W_fc^T + b_fc ----------------
__global__ __launch_bounds__(256) void k3_em(const float* __restrict__ Wfc,
                                             const float* __restrict__ bfc,
                                             float* __restrict__ ws)
{
    __shared__ float llds[15][404];
    __shared__ float wlds[17][404];
    const float* lstm = ws + LSTM_OFF;
    float* em = ws + EM_OFF;
    int n0 = blockIdx.x * 15;
    int tid = threadIdx.x;
    for (int idx = tid; idx < 15 * 400; idx += 256) {
        int r = idx / 400, c = idx % 400;
        int n = n0 + r;
        llds[r][c] = (n < BATCH * TLEN) ? lstm[(size_t)n * 400 + c] : 0.f;
    }
    for (int idx = tid; idx < 17 * 400; idx += 256) {
        int r = idx / 400, c = idx % 400;
        wlds[r][c] = Wfc[r * 400 + c];
    }
    __syncthreads();
    if (tid < 255) {
        int tk = tid / 17, k = tid % 17;
        int n = n0 + tk;
        if (n < BATCH * TLEN) {
            float acc = 0.f;
#pragma unroll
            for (int i = 0; i < 100; i++) {
                float4 a  = *(const float4*)&llds[tk][4 * i];
                float4 wv = *(const float4*)&wlds[k][4 * i];
                acc += a.x * wv.x + a.y * wv.y + a.z * wv.z + a.w * wv.w;
            }
            em[(size_t)n * KTAG + k] = acc + bfc[k];
        }
    }
}

// ---------------- K4: bin_scores = mean_t(lstm_out) @ W_bin^T + b_bin ----------------
__global__ __launch_bounds__(256) void k4_bin(const float* __restrict__ Wbin,
                                              const float* __restrict__ bbin,
                                              float* __restrict__ ws,
                                              float* __restrict__ out)
{
    int b = blockIdx.x, tid = threadIdx.x;
    const float* lstm = ws + LSTM_OFF;
    __shared__ float m_lds[400];
    float a0 = 0.f, a1 = 0.f;
#pragma unroll 4
    for (int t = 0; t < TLEN; t++) {
        const float* rowp = lstm + ((size_t)t * BATCH + b) * 400;
        a0 += rowp[tid];
        if (tid < 144) a1 += rowp[256 + tid];
    }
    m_lds[tid] = a0 * (1.f / 512.f);
    if (tid < 144) m_lds[256 + tid] = a1 * (1.f / 512.f);
    __syncthreads();
    int wv = tid >> 6, lane = tid & 63;
    if (wv < 2) {
        float p = 0.f;
        for (int j = lane; j < 400; j += 64) p += m_lds[j] * Wbin[wv * 400 + j];
#pragma unroll
        for (int off = 32; off > 0; off >>= 1) p += __shfl_down(p, off);
        if (lane == 0) out[(size_t)BATCH * TLEN + b * 2 + wv] = p + bbin[wv];
    }
}

// ---------------- K5: masked Viterbi decode + traceback ----------------
__global__ __launch_bounds__(64) void k5_vit(const int* __restrict__ masks,
                                             const float* __restrict__ trans,
                                             const float* __restrict__ startv,
                                             const float* __restrict__ endv,
                                             const float* __restrict__ ws,
                                             float* __restrict__ out)
{
    int b = blockIdx.x, lane = threadIdx.x;
    const float* em = ws + EM_OFF;
    __shared__ float emlds[TLEN * KTAG];
    __shared__ unsigned char bpl[TLEN * KTAG];
    __shared__ int mlds[TLEN];
    __shared__ unsigned char tagl[TLEN];
    __shared__ float slds[KTAG];
    __shared__ float fin[KTAG];

    for (int idx = lane; idx < TLEN * KTAG; idx += 64) {
        int tt = idx / KTAG, j = idx - tt * KTAG;
        emlds[idx] = em[((size_t)tt * BATCH + b) * KTAG + j];
    }
    for (int idx = lane; idx < TLEN; idx += 64) mlds[idx] = masks[(size_t)b * TLEN + idx];
    bool on = lane < KTAG;
    float tr[KTAG];
    if (on) {
#pragma unroll
        for (int i = 0; i < KTAG; i++) tr[i] = trans[i * KTAG + lane];
    }
    __syncthreads();
    float sown = 0.f;
    if (on) { sown = startv[lane] + emlds[lane]; slds[lane] = sown; }
    __syncthreads();
#pragma unroll 1
    for (int t = 1; t < TLEN; t++) {
        int m = mlds[t];
        float ns = sown; int idx = lane;
        if (on) {
            float best = -3.4e38f; int bi = 0;
#pragma unroll
            for (int i = 0; i < KTAG; i++) {
                float vv = slds[i] + tr[i];
                if (vv > best) { best = vv; bi = i; }   // strict > => first max (matches jnp.argmax)
            }
            if (m != 0) { ns = best + emlds[t * KTAG + lane]; idx = bi; }
        }
        __syncthreads();
        if (on) { sown = ns; slds[lane] = ns; bpl[t * KTAG + lane] = (unsigned char)idx; }
        __syncthreads();
    }
    if (on) fin[lane] = sown + endv[lane];
    __syncthreads();
    if (lane == 0) {
        float bb = -3.4e38f; int bi = 0;
#pragma unroll
        for (int i = 0; i < KTAG; i++) if (fin[i] > bb) { bb = fin[i]; bi = i; }
        int cur = bi;
        tagl[TLEN - 1] = (unsigned char)cur;
        for (int t = TLEN - 1; t >= 1; t--) {
            cur = bpl[t * KTAG + cur];
            tagl[t - 1] = (unsigned char)cur;
        }
    }
    __syncthreads();
    for (int s = lane; s < TLEN; s += 64) out[(size_t)b * TLEN + s] = (float)tagl[s];
}

extern "C" void kernel_launch(void* const* d_in, const int* in_sizes, int n_in,
                              void* d_out, int out_size, void* d_ws, size_t ws_size,
                              hipStream_t stream)
{
    (void)in_sizes; (void)n_in; (void)out_size; (void)ws_size;
    const int*   sentence = (const int*)d_in[0];
    const int*   masks    = (const int*)d_in[1];
    const float* emb      = (const float*)d_in[2];
    const float* Wih_f    = (const float*)d_in[3];
    const float* Whh_f    = (const float*)d_in[4];
    const float* b_f      = (const float*)d_in[5];
    const float* Wih_b    = (const float*)d_in[6];
    const float* Whh_b    = (const float*)d_in[7];
    const float* b_b      = (const float*)d_in[8];
    const float* W_fc     = (const float*)d_in[9];
    const float* b_fc     = (const float*)d_in[10];
    const float* W_bin    = (const float*)d_in[11];
    const float* b_bin    = (const float*)d_in[12];
    const float* trans    = (const float*)d_in[13];
    const float* startv   = (const float*)d_in[14];
    const float* endv     = (const float*)d_in[15];
    float* ws  = (float*)d_ws;
    float* out = (float*)d_out;

    k0_pack<<<313, 256, 0, stream>>>(Whh_f, Whh_b, ws);
    k1_proj<<<626, 256, 0, stream>>>(emb, Wih_f, Wih_b, ws);
    k2_lstm<<<64, 512, 0, stream>>>(sentence, b_f, b_b, ws);
    k3_em<<<4370, 256, 0, stream>>>(W_fc, b_fc, ws);
    k4_bin<<<128, 256, 0, stream>>>(W_bin, b_bin, ws, out);
    k5_vit<<<128, 64, 0, stream>>>(masks, trans, startv, endv, ws, out);
}